// Round 4
// baseline (465.608 us; speedup 1.0000x reference)
//
#include <hip/hip_runtime.h>
#include <hip/hip_cooperative_groups.h>
#include <math.h>

namespace cg = cooperative_groups;

#define NANCH 87296
#define NF 4256        // 1000*4 + 256 finalists
#define CAPD 128       // max neighbors per column
#define NBINS 65536
#define NITER 16       // 15 scan iterations + initial keep
#define BCAP 2048      // boundary-bin buffer per level (valid score-ties only)
#define EC 12288       // LDS edge cap for NMS CSR copy
#define NCH 682        // 128-anchor chunks; level boundaries are multiples of 128
#define CHA 128
#define BIN_NEG 0x407Fu  // fkey(-1.0f) >> 16
#define NBLOCK 256
#define NTHR 1024

struct InPtrs {
    const float* cls[5];
    const float* reg[5];
    const float* loc;
};

// workspace layout
constexpr size_t SZ_HIST  = 5ull * NBINS * 4;
constexpr size_t OFF_HIST = 0;
constexpr size_t OFF_CNT  = OFF_HIST + SZ_HIST;
constexpr size_t OFF_CTR  = OFF_CNT + (size_t)NF * 4;   // [0]=finCount,[1..5]=bCount
constexpr size_t ZERO_SZ  = OFF_CTR + 64;
constexpr size_t OFF_SBITS = ((ZERO_SZ + 255) / 256) * 256;
constexpr size_t OFF_CLSV  = OFF_SBITS + (size_t)NANCH * 4;
constexpr size_t OFF_PAR   = OFF_CLSV + (size_t)NANCH * 4;  // B*[5]@0,r*[5]@8,rNeg[5]@16
constexpr size_t OFF_INVB  = OFF_PAR + 128;                 // per-chunk invalid counts (682)
constexpr size_t OFF_INVO  = OFF_INVB + (size_t)NCH * 4;    // scanned offsets
constexpr size_t OFF_FINK  = ((OFF_INVO + (size_t)NCH * 4 + 255) / 256) * 256;
constexpr size_t OFF_BBUF  = OFF_FINK + (size_t)NF * 8;
constexpr size_t OFF_SBOX  = OFF_BBUF + 5ull * BCAP * 8;
constexpr size_t OFF_SSC   = OFF_SBOX + (size_t)NF * 16;
constexpr size_t OFF_SCV   = OFF_SSC + (size_t)NF * 4;
constexpr size_t OFF_SAR   = OFF_SCV + (size_t)NF * 4;
constexpr size_t OFF_NBR   = OFF_SAR + (size_t)NF * 4;

__device__ __forceinline__ void lvl_of(int a, int& lev, int& idx) {
    if (a < 65536)      { lev = 0; idx = a; }
    else if (a < 81920) { lev = 1; idx = a - 65536; }
    else if (a < 86016) { lev = 2; idx = a - 81920; }
    else if (a < 87040) { lev = 3; idx = a - 86016; }
    else                { lev = 4; idx = a - 87040; }
}
__device__ __forceinline__ void chunk_lev(int c, int& lev, int& idx0) {
    if (c < 512)      { lev = 0; idx0 = c << 7; }
    else if (c < 640) { lev = 1; idx0 = (c - 512) << 7; }
    else if (c < 672) { lev = 2; idx0 = (c - 640) << 7; }
    else if (c < 680) { lev = 3; idx0 = (c - 672) << 7; }
    else              { lev = 4; idx0 = (c - 680) << 7; }
}
__device__ __forceinline__ unsigned int fkey(float f) {
    unsigned int u = __float_as_uint(f);
    return u ^ ((u & 0x80000000u) ? 0xFFFFFFFFu : 0x80000000u);
}
__device__ __forceinline__ float funkey(unsigned int k) {
    return __uint_as_float(k ^ ((k & 0x80000000u) ? 0x80000000u : 0xFFFFFFFFu));
}

// LDS overlay offsets for the NMS phase (max user = 62,760 B < 64 KB)
#define U_OFF   0            // uint[NF+1]   17040
#define U_DEGS  17040        // ushort[NF]    8512
#define U_EDGE  25552        // ushort[EC]   24576
#define U_BUFA  50128        // uchar[NF]     4256
#define U_BUFB  54384        // uchar[NF]     4256
#define U_CSUM  58640        // uint[1024]    4096
#define U_PLOC  62736        // float[6]

__global__ __launch_bounds__(NTHR, 4) void mega(InPtrs P, char* ws, float* out) {
    __shared__ __align__(16) char U[62784];
    __shared__ unsigned int wInvS[2], wFinS[2], wBS[2], baseFinS, baseBS;
    cg::grid_group grid = cg::this_grid();
    const int t = threadIdx.x;
    const int b = blockIdx.x;
    const int lane = t & 63;
    const int wid = t >> 6;

    unsigned int* hist = (unsigned int*)(ws + OFF_HIST);
    unsigned int* cnt  = (unsigned int*)(ws + OFF_CNT);
    unsigned int* ctrs = (unsigned int*)(ws + OFF_CTR);
    unsigned int* sbits = (unsigned int*)(ws + OFF_SBITS);
    unsigned int* clsv  = (unsigned int*)(ws + OFF_CLSV);
    unsigned int* params = (unsigned int*)(ws + OFF_PAR);
    unsigned int* invChunk = (unsigned int*)(ws + OFF_INVB);
    unsigned int* invOff   = (unsigned int*)(ws + OFF_INVO);
    unsigned long long* finKeys = (unsigned long long*)(ws + OFF_FINK);
    unsigned long long* bBuf    = (unsigned long long*)(ws + OFF_BBUF);
    float4* sBox  = (float4*)(ws + OFF_SBOX);
    float* sScore = (float*)(ws + OFF_SSC);
    unsigned int* sCV = (unsigned int*)(ws + OFF_SCV);
    float* sArea  = (float*)(ws + OFF_SAR);
    unsigned short* nbr = (unsigned short*)(ws + OFF_NBR);

    // ============================ PHASE 1: score/argmax/hist ================
    // Chunk = 128 anchors = 10240 floats staged via coalesced float2 loads.
    for (int c = b; c < NCH; c += NBLOCK) {
        int clev, idx0; chunk_lev(c, clev, idx0);
        const float2* src2 = (const float2*)(P.cls[clev] + (size_t)idx0 * 80);
        float2* stg2 = (float2*)U;
        #pragma unroll
        for (int r = 0; r < 5; ++r) stg2[t + NTHR * r] = src2[t + NTHR * r];
        __syncthreads();
        unsigned int* wv = (unsigned int*)(U + 40960);
        if (t < 512) {
            int n = t >> 2, k = t & 3;
            const float4* stg4 = (const float4*)U;
            float best = -INFINITY; int bi = 0;
            #pragma unroll
            for (int q = 0; q < 5; ++q) {
                float4 v = stg4[n * 20 + q * 4 + k];
                int c0 = q * 16 + k * 4;
                if (v.x > best) { best = v.x; bi = c0 + 0; }
                if (v.y > best) { best = v.y; bi = c0 + 1; }
                if (v.z > best) { best = v.z; bi = c0 + 2; }
                if (v.w > best) { best = v.w; bi = c0 + 3; }
            }
            #pragma unroll
            for (int m = 1; m < 4; m <<= 1) {
                float ob = __shfl_xor(best, m, 64);
                int  obi = __shfl_xor(bi, m, 64);
                if (ob > best || (ob == best && obi < bi)) { best = ob; bi = obi; }
            }
            bool lead = (k == 0);
            unsigned int valid = 0;
            if (lead) {
                float score = 1.0f / (1.0f + expf(-best));
                valid = (score > 0.05f) ? 1u : 0u;
                float psm = valid ? score : -1.0f;
                unsigned int sb = fkey(psm);
                int a = c * CHA + n;
                sbits[a] = sb;
                clsv[a] = (unsigned int)(bi + 1) | (valid << 31);
                if (valid) atomicAdd(&hist[(size_t)clev * NBINS + (sb >> 16)], 1u);
            }
            unsigned long long mv = __ballot(lead && valid);
            if (lane == 0) wv[wid] = (unsigned int)__popcll(mv);
        }
        __syncthreads();
        if (t == 0) {
            unsigned int s = 0;
            #pragma unroll
            for (int i = 0; i < 8; ++i) s += wv[i];
            invChunk[c] = (unsigned int)CHA - s;
        }
        __syncthreads();
    }
    grid.sync();

    // ============================ PHASE 2: bin scans ========================
    if (b < 5) {
        unsigned int K = (b == 4) ? 256u : 1000u;
        const unsigned int* h = hist + (size_t)b * NBINS;
        const uint4* h4 = (const uint4*)h;
        unsigned int* seg = (unsigned int*)U;
        unsigned int* suf = (unsigned int*)(U + 4096);
        unsigned int s = 0;
        #pragma unroll
        for (int q = 0; q < 16; ++q) {
            uint4 v = h4[t * 16 + q];
            s += v.x + v.y + v.z + v.w;
        }
        seg[t] = s; suf[t] = s;
        __syncthreads();
        for (int off = 1; off < 1024; off <<= 1) {
            unsigned int v = suf[t];
            unsigned int add = (t + off < 1024) ? suf[t + off] : 0u;
            __syncthreads();
            suf[t] = v + add;
            __syncthreads();
        }
        unsigned int totValid = suf[0];
        if (totValid >= K) {
            unsigned int excl = suf[t] - seg[t];
            if (excl < K && excl + seg[t] >= K) {
                unsigned int cum = excl;
                for (int q = 63; q >= 0; --q) {
                    unsigned int cc = h[t * 64 + q];
                    if (cum + cc >= K) {
                        params[b] = (unsigned int)(t * 64 + q);
                        params[8 + b] = K - cum;
                        params[16 + b] = 0;
                        break;
                    }
                    cum += cc;
                }
            }
        } else if (t == 0) {
            params[b] = BIN_NEG; params[8 + b] = 0; params[16 + b] = K - totValid;
        }
    } else if (b == 5) {
        unsigned int* sv = (unsigned int*)U;
        unsigned int* orig = (unsigned int*)(U + 4096);
        unsigned int v = (t < NCH) ? invChunk[t] : 0u;
        sv[t] = v; orig[t] = v;
        __syncthreads();
        for (int off = 1; off < 1024; off <<= 1) {
            unsigned int add = (t >= off) ? sv[t - off] : 0u;
            __syncthreads();
            sv[t] += add;
            __syncthreads();
        }
        if (t < NCH) {
            int segStart = (t < 512) ? 0 : (t < 640) ? 512 : (t < 672) ? 640
                         : (t < 680) ? 672 : 680;
            invOff[t] = sv[t] - orig[t] - (segStart > 0 ? sv[segStart - 1] : 0u);
        }
    }
    grid.sync();

    // ============================ PHASE 3: compact ==========================
    for (int c = b; c < NCH; c += NBLOCK) {
        int clev, idx0; chunk_lev(c, clev, idx0);
        unsigned int sb = 0, cv = 0, valid = 0, myInvPre = 0, pFin = 0, pB = 0;
        bool isFin = false, isB = false;
        if (t < CHA) {
            int a = c * CHA + t;
            sb = sbits[a]; cv = clsv[a];
            valid = cv >> 31;
            unsigned long long mInv = __ballot(valid == 0u);
            if (lane == 0) wInvS[wid] = (unsigned int)__popcll(mInv);
            myInvPre = (unsigned int)__popcll(mInv & ((1ull << lane) - 1ull));
        }
        __syncthreads();
        if (t < CHA) {
            unsigned int h16 = sb >> 16;
            unsigned int Bs = params[clev];
            unsigned int rNeg = params[16 + clev];
            unsigned int invRank = invOff[c] + myInvPre + (wid ? wInvS[0] : 0u);
            if (valid) { isFin = (h16 > Bs); isB = (h16 == Bs); }
            else       { isFin = (Bs == BIN_NEG) && (invRank < rNeg); }
            unsigned long long mFin = __ballot(isFin);
            unsigned long long mB   = __ballot(isB);
            if (lane == 0) {
                wFinS[wid] = (unsigned int)__popcll(mFin);
                wBS[wid]   = (unsigned int)__popcll(mB);
            }
            unsigned long long lt = (1ull << lane) - 1ull;
            pFin = (unsigned int)__popcll(mFin & lt);
            pB   = (unsigned int)__popcll(mB & lt);
        }
        __syncthreads();
        if (t == 0) {
            unsigned int tf = wFinS[0] + wFinS[1];
            unsigned int tb = wBS[0] + wBS[1];
            baseFinS = tf ? atomicAdd(&ctrs[0], tf) : 0u;
            baseBS   = tb ? atomicAdd(&ctrs[1 + clev], tb) : 0u;
        }
        __syncthreads();
        if (t < CHA && (isFin || isB)) {
            int a = c * CHA + t;
            int lev, idx; lvl_of(a, lev, idx);
            unsigned int composite = ((unsigned int)lev << 16) | (unsigned int)idx;
            unsigned int inv = (~composite) & 0x7FFFFu;
            unsigned int low = (inv << 13) | (valid << 7) | (cv & 0x7Fu);
            unsigned long long key = ((unsigned long long)sb << 32) | low;
            if (isFin) {
                unsigned int p = baseFinS + pFin + (wid ? wFinS[0] : 0u);
                if (p < NF) finKeys[p] = key;
            } else {
                unsigned int p = baseBS + pB + (wid ? wBS[0] : 0u);
                if (p < BCAP) bBuf[(size_t)clev * BCAP + p] = key;
            }
        }
        __syncthreads();
    }
    grid.sync();

    // ============================ PHASE 4: boundary ties ====================
    if (b < 5) {
        unsigned long long* kb = (unsigned long long*)U;
        unsigned int bc = ctrs[1 + b];
        int n = (bc > BCAP) ? BCAP : (int)bc;
        int r = (int)params[8 + b];
        if (r > n) r = n;
        int m = 1; while (m < n) m <<= 1;
        for (int i = t; i < m; i += NTHR)
            kb[i] = (i < n) ? bBuf[(size_t)b * BCAP + i] : 0ull;
        __syncthreads();
        for (int len = 2; len <= m; len <<= 1) {
            for (int st = len >> 1; st > 0; st >>= 1) {
                for (int i = t; i < m; i += NTHR) {
                    int j = i ^ st;
                    if (j > i) {
                        unsigned long long a = kb[i], bb2 = kb[j];
                        bool up = ((i & len) == 0);
                        if (up ? (a < bb2) : (a > bb2)) { kb[i] = bb2; kb[j] = a; }
                    }
                }
                __syncthreads();
            }
        }
        for (int i = t; i < r; i += NTHR) {
            unsigned int p = atomicAdd(&ctrs[0], 1u);
            if (p < NF) finKeys[p] = kb[i];
        }
    }
    grid.sync();

    // ============================ PHASE 5: rank + decode ====================
    {
        unsigned long long* keys = (unsigned long long*)U;
        for (int i = t; i < NF; i += NTHR) keys[i] = finKeys[i];
        __syncthreads();
        for (int f = b * 16 + wid; f < NF; f += NBLOCK * 16) {
            unsigned long long my = keys[f];
            unsigned int cgt = 0;
            for (int i = lane; i < NF; i += 64) cgt += (keys[i] > my) ? 1u : 0u;
            #pragma unroll
            for (int m = 1; m < 64; m <<= 1) cgt += __shfl_xor(cgt, m, 64);
            if (lane == 0) {
                unsigned int r = cgt;
                unsigned int sb  = (unsigned int)(my >> 32);
                unsigned int low = (unsigned int)my;
                unsigned int composite = (~(low >> 13)) & 0x7FFFFu;
                int lev = composite >> 16;
                int idx = composite & 0xFFFF;
                float4 bx = ((const float4*)P.reg[lev])[idx];
                float vy1 = P.loc[0], vx1 = P.loc[1], vy2 = P.loc[2], vx2 = P.loc[3];
                float y1 = fmaxf(bx.x, vy1), x1 = fmaxf(bx.y, vx1);
                float y2 = fminf(bx.z, vy2), x2 = fminf(bx.w, vx2);
                float area = __fmul_rn(fmaxf(y2 - y1, 0.0f), fmaxf(x2 - x1, 0.0f));
                unsigned int valid = (low >> 7) & 1u;
                sBox[r] = make_float4(y1, x1, y2, x2);
                sScore[r] = valid ? funkey(sb) : 0.0f;
                sCV[r] = (low & 0x7Fu) | (valid << 31);
                sArea[r] = area;
            }
        }
    }
    grid.sync();

    // ============================ PHASE 6: adjacency ========================
    {
        float4* cb = (float4*)U;
        float4* rb = (float4*)(U + 1024);
        float*  ca = (float*)(U + 2048);
        float*  ra = (float*)(U + 2304);
        for (int L = b; L < 2278; L += NBLOCK) {
            float fr = sqrtf(8.0f * (float)L + 1.0f);
            int jt = (int)((fr - 1.0f) * 0.5f);
            while ((jt + 1) * (jt + 2) / 2 <= L) jt++;
            while (jt * (jt + 1) / 2 > L) jt--;
            int it = L - jt * (jt + 1) / 2;
            if (t < 64) {
                int j = jt * 64 + t;
                if (j < NF) { cb[t] = sBox[j]; ca[t] = sArea[j]; }
                int i = it * 64 + t;
                if (i < NF) { rb[t] = sBox[i]; ra[t] = sArea[i]; }
            }
            __syncthreads();
            int j = jt * 64 + lane;
            if (j < NF) {
                float4 B = cb[lane]; float ab = ca[lane];
                int li0 = wid * 4;
                #pragma unroll
                for (int u = 0; u < 4; ++u) {
                    int li = li0 + u;
                    int i = it * 64 + li;
                    if (i < j) {
                        float4 A = rb[li]; float aa = ra[li];
                        float iy1 = fmaxf(A.x, B.x), ix1 = fmaxf(A.y, B.y);
                        float iy2 = fminf(A.z, B.z), ix2 = fminf(A.w, B.w);
                        float ih = fmaxf(iy2 - iy1, 0.0f), iw = fmaxf(ix2 - ix1, 0.0f);
                        float inter = __fmul_rn(ih, iw);
                        float uni = __fsub_rn(__fadd_rn(aa, ab), inter);
                        float iou = __fdiv_rn(inter, fmaxf(uni, 1e-9f));
                        if (iou > 0.5f) {
                            unsigned int p = atomicAdd(&cnt[j], 1u);
                            if (p < CAPD) nbr[(size_t)j * CAPD + p] = (unsigned short)i;
                        }
                    }
                }
            }
            __syncthreads();
        }
    }
    grid.sync();

    // ============================ PHASE 7: NMS + emit (block 0) =============
    if (b == 0) {
        unsigned int* off = (unsigned int*)(U + U_OFF);
        unsigned short* degs = (unsigned short*)(U + U_DEGS);
        unsigned short* edges = (unsigned short*)(U + U_EDGE);
        unsigned char* bufA = (unsigned char*)(U + U_BUFA);
        unsigned char* bufB = (unsigned char*)(U + U_BUFB);
        unsigned int* csum = (unsigned int*)(U + U_CSUM);
        float* ploc = (float*)(U + U_PLOC);
        if (t < 6) ploc[t] = P.loc[t];
        for (int j = t; j < NF; j += NTHR) {
            unsigned int d = cnt[j]; if (d > CAPD) d = CAPD;
            degs[j] = (unsigned short)d;
            bufA[j] = 1;
        }
        __syncthreads();
        const int CH = 5;
        {
            unsigned int dq[CH]; unsigned int s = 0;
            #pragma unroll
            for (int q = 0; q < CH; ++q) {
                int j = t * CH + q;
                unsigned int d = (j < NF) ? (unsigned int)degs[j] : 0u;
                dq[q] = d; s += d;
            }
            csum[t] = s;
            __syncthreads();
            for (int o = 1; o < 1024; o <<= 1) {
                unsigned int v = csum[t];
                unsigned int add = (t >= o) ? csum[t - o] : 0u;
                __syncthreads();
                csum[t] = v + add;
                __syncthreads();
            }
            unsigned int base = csum[t] - s;
            #pragma unroll
            for (int q = 0; q < CH; ++q) {
                int j = t * CH + q;
                if (j < NF) { off[j] = base; base += dq[q]; }
            }
            if (t == 1023) off[NF] = csum[1023];
        }
        __syncthreads();
        unsigned int E = off[NF];
        bool useLds = (E <= (unsigned int)EC);
        if (useLds) {
            for (int j = t; j < NF; j += NTHR) {
                unsigned int o = off[j];
                unsigned int d = degs[j];
                const unsigned short* nl = nbr + (size_t)j * CAPD;
                for (unsigned int e = 0; e < d; ++e) edges[o + e] = nl[e];
            }
        }
        __syncthreads();
        unsigned char* cur = bufA; unsigned char* nxt = bufB;
        for (int itr = 0; itr < NITER; ++itr) {
            if (useLds) {
                for (int j = t; j < NF; j += NTHR) {
                    unsigned int d = degs[j];
                    unsigned int o = off[j];
                    unsigned char kp = 1;
                    for (unsigned int e = 0; e < d; ++e)
                        if (cur[edges[o + e]]) { kp = 0; break; }
                    nxt[j] = kp;
                }
            } else {
                for (int j = t; j < NF; j += NTHR) {
                    unsigned int d = degs[j];
                    const unsigned short* nl = nbr + (size_t)j * CAPD;
                    unsigned char kp = 1;
                    for (unsigned int e = 0; e < d; ++e)
                        if (cur[nl[e]]) { kp = 0; break; }
                    nxt[j] = kp;
                }
            }
            __syncthreads();
            unsigned char* tm = cur; cur = nxt; nxt = tm;
        }
        int base = t * CH;
        unsigned char kf[CH];
        unsigned int sum = 0;
        #pragma unroll
        for (int q = 0; q < CH; ++q) {
            int j = base + q;
            unsigned char v = 0;
            if (j < NF) v = cur[j] & (unsigned char)(sCV[j] >> 31);
            kf[q] = v; sum += v;
        }
        csum[t] = sum;
        __syncthreads();
        for (int o = 1; o < 1024; o <<= 1) {
            unsigned int v = csum[t];
            unsigned int add = (t >= o) ? csum[t - o] : 0u;
            __syncthreads();
            csum[t] = v + add;
            __syncthreads();
        }
        unsigned int keptTot = csum[1023];
        unsigned int run = csum[t] - sum;
        float vy1 = ploc[0], vx1 = ploc[1], vy2 = ploc[2], vx2 = ploc[3];
        float sy = ploc[4] / fmaxf(vy2 - vy1, 1e-6f);
        float sx = ploc[5] / fmaxf(vx2 - vx1, 1e-6f);
        #pragma unroll
        for (int q = 0; q < CH; ++q) {
            int j = base + q;
            if (j >= NF) break;
            unsigned int slot = 0xFFFFFFFFu;
            float sc = 0.0f;
            if (kf[q]) {
                if (run < 100u) { slot = run; sc = sScore[j]; }
                run++;
            } else if (keptTot < 100u) {
                unsigned int nk = (unsigned int)j - run;
                unsigned int s2 = keptTot + nk;
                if (s2 < 100u) { slot = s2; sc = 0.0f; }
            }
            if (slot < 100u) {
                float4 bx = sBox[j];
                out[slot * 4 + 0] = (bx.x - vy1) * sy;
                out[slot * 4 + 1] = (bx.y - vx1) * sx;
                out[slot * 4 + 2] = (bx.z - vy1) * sy;
                out[slot * 4 + 3] = (bx.w - vx1) * sx;
                out[400 + slot] = (float)(sCV[j] & 0x7Fu);
                out[500 + slot] = sc;
            }
        }
    }
}

extern "C" void kernel_launch(void* const* d_in, const int* in_sizes, int n_in,
                              void* d_out, int out_size, void* d_ws, size_t ws_size,
                              hipStream_t stream) {
    (void)n_in; (void)out_size; (void)ws_size;
    InPtrs P;
    bool inter = (in_sizes[1] == 65536 * 4);
    for (int s = 0; s < 5; ++s) {
        P.cls[s] = (const float*)d_in[inter ? 2 * s : s];
        P.reg[s] = (const float*)d_in[inter ? 2 * s + 1 : 5 + s];
    }
    P.loc = (const float*)d_in[10];

    char* wsp = (char*)d_ws;
    float* outp = (float*)d_out;
    hipMemsetAsync(d_ws, 0, ZERO_SZ, stream);
    void* args[] = { (void*)&P, (void*)&wsp, (void*)&outp };
    hipLaunchCooperativeKernel((const void*)mega, dim3(NBLOCK), dim3(NTHR),
                               args, 0, stream);
}

// Round 5
// 253.731 us; speedup vs baseline: 1.8350x; 1.8350x over previous
//
#include <hip/hip_runtime.h>
#include <math.h>

#define NANCH 87296
#define NF 4256        // 1000*4 + 256 finalists
#define CAPD 128       // max neighbors per column
#define NBINS 65536
#define NITER 16       // 15 scan iterations + initial keep
#define BCAP 2048      // boundary-bin buffer per level
#define EC 12288       // LDS edge cap for k7 CSR copy
#define NBLK 341       // 256-anchor blocks; level boundaries are multiples of 256
#define BIN_NEG 0x407Fu  // fkey(-1.0f) >> 16

struct InPtrs {
    const float* cls[5];
    const float* reg[5];
    const float* loc;
};

// workspace layout
constexpr size_t SZ_HIST  = 5ull * NBINS * 4;
constexpr size_t OFF_HIST = 0;
constexpr size_t OFF_CNT  = OFF_HIST + SZ_HIST;
constexpr size_t OFF_CTR  = OFF_CNT + (size_t)NF * 4;   // [0]=finCount,[1..5]=bCount
constexpr size_t ZERO_SZ  = OFF_CTR + 64;
constexpr size_t OFF_SBITS = ((ZERO_SZ + 255) / 256) * 256;
constexpr size_t OFF_CLSV  = OFF_SBITS + (size_t)NANCH * 4;
constexpr size_t OFF_PAR   = OFF_CLSV + (size_t)NANCH * 4;  // B*[5]@0,r*[5]@8,rNeg[5]@16
constexpr size_t OFF_INVB  = OFF_PAR + 128;                 // per-block invalid counts
constexpr size_t OFF_INVO  = OFF_INVB + (size_t)NBLK * 4;   // scanned offsets
constexpr size_t OFF_FINK  = ((OFF_INVO + (size_t)NBLK * 4 + 255) / 256) * 256;
constexpr size_t OFF_BBUF  = OFF_FINK + (size_t)NF * 8;
constexpr size_t OFF_SBOX  = OFF_BBUF + 5ull * BCAP * 8;
constexpr size_t OFF_SSC   = OFF_SBOX + (size_t)NF * 16;
constexpr size_t OFF_SCV   = OFF_SSC + (size_t)NF * 4;
constexpr size_t OFF_SAR   = OFF_SCV + (size_t)NF * 4;
constexpr size_t OFF_NBR   = OFF_SAR + (size_t)NF * 4;

__device__ __forceinline__ void lvl_of(int a, int& lev, int& idx) {
    if (a < 65536)      { lev = 0; idx = a; }
    else if (a < 81920) { lev = 1; idx = a - 65536; }
    else if (a < 86016) { lev = 2; idx = a - 81920; }
    else if (a < 87040) { lev = 3; idx = a - 86016; }
    else                { lev = 4; idx = a - 87040; }
}

__device__ __forceinline__ unsigned int fkey(float f) {
    unsigned int u = __float_as_uint(f);
    return u ^ ((u & 0x80000000u) ? 0xFFFFFFFFu : 0x80000000u);
}
__device__ __forceinline__ float funkey(unsigned int k) {
    return __uint_as_float(k ^ ((k & 0x80000000u) ? 0x80000000u : 0xFFFFFFFFu));
}
// bit-reversed bin address: consecutive (hot) bins -> distant cache lines ->
// parallel across L2 slices instead of serializing on ~5 lines.
__device__ __forceinline__ unsigned int binaddr(unsigned int bin) {
    return __brev(bin) >> 16;
}

// ---------------------------------------------------------------- K1
// 4 threads/anchor, 256 anchors/block. Histogram atomics go to bit-reversed
// bin addresses (see binaddr) — removes the L2 same-line atomic drain that
// pinned this kernel at ~100 us regardless of implementation.
__global__ __launch_bounds__(1024) void k1_score(InPtrs P, unsigned int* hist,
        unsigned int* sbits, unsigned int* clsv, unsigned int* invBlk) {
    int t = threadIdx.x;
    int a = blockIdx.x * 256 + (t >> 2);
    int k = t & 3;
    int lev, idx; lvl_of(a, lev, idx);
    const float4* row = (const float4*)(P.cls[lev] + (size_t)idx * 80);
    float best = -INFINITY; int bi = 0;
    #pragma unroll
    for (int q = 0; q < 5; ++q) {
        float4 v = row[q * 4 + k];
        int c0 = q * 16 + k * 4;
        if (v.x > best) { best = v.x; bi = c0 + 0; }
        if (v.y > best) { best = v.y; bi = c0 + 1; }
        if (v.z > best) { best = v.z; bi = c0 + 2; }
        if (v.w > best) { best = v.w; bi = c0 + 3; }
    }
    #pragma unroll
    for (int m = 1; m < 4; m <<= 1) {
        float ob = __shfl_xor(best, m, 64);
        int  obi = __shfl_xor(bi, m, 64);
        if (ob > best || (ob == best && obi < bi)) { best = ob; bi = obi; }
    }
    bool lead = (k == 0);
    unsigned int valid = 0;
    if (lead) {
        float score = 1.0f / (1.0f + expf(-best));
        valid = (score > 0.05f) ? 1u : 0u;
        float psm = valid ? score : -1.0f;
        unsigned int sb = fkey(psm);
        sbits[a] = sb;
        clsv[a] = (unsigned int)(bi + 1) | (valid << 31);
        if (valid) atomicAdd(&hist[(size_t)lev * NBINS + binaddr(sb >> 16)], 1u);
    }
    __shared__ unsigned int wv[16];
    unsigned long long mv = __ballot(lead && valid);
    int lane = t & 63, w = t >> 6;
    if (lane == 0) wv[w] = (unsigned int)__popcll(mv);
    __syncthreads();
    if (t == 0) {
        unsigned int s = 0;
        #pragma unroll
        for (int i = 0; i < 16; ++i) s += wv[i];
        invBlk[blockIdx.x] = 256u - s;
    }
}

// ---------------------------------------------------------------- K2
// blocks 0-4: per-level descending bin scan (gathers through binaddr).
// block 5: segmented exclusive scan of per-block invalid counts.
__global__ __launch_bounds__(1024) void k2_scan(const unsigned int* hist,
        const unsigned int* invBlk, unsigned int* params, unsigned int* invOff) {
    int t = threadIdx.x;
    if (blockIdx.x == 5) {
        __shared__ unsigned int sv[512];
        __shared__ unsigned int orig[512];
        if (t < 512) {
            unsigned int v = (t < NBLK) ? invBlk[t] : 0u;
            sv[t] = v; orig[t] = v;
        }
        __syncthreads();
        for (int off = 1; off < 512; off <<= 1) {
            unsigned int add = 0;
            if (t < 512 && t >= off) add = sv[t - off];
            __syncthreads();
            if (t < 512) sv[t] += add;
            __syncthreads();
        }
        if (t < NBLK) {
            int segStart = (t < 256) ? 0 : (t < 320) ? 256 : (t < 336) ? 320
                         : (t < 340) ? 336 : 340;
            invOff[t] = sv[t] - orig[t] - (segStart > 0 ? sv[segStart - 1] : 0u);
        }
        return;
    }
    int lev = blockIdx.x;
    unsigned int K = (lev == 4) ? 256u : 1000u;
    const unsigned int* h = hist + (size_t)lev * NBINS;
    __shared__ unsigned int seg[1024];
    __shared__ unsigned int suf[1024];
    unsigned int s = 0;
    for (int b = 0; b < 64; ++b) s += h[binaddr((unsigned int)(t * 64 + b))];
    seg[t] = s;
    suf[t] = s;
    __syncthreads();
    for (int off = 1; off < 1024; off <<= 1) {
        unsigned int v = suf[t];
        unsigned int add = (t + off < 1024) ? suf[t + off] : 0u;
        __syncthreads();
        suf[t] = v + add;
        __syncthreads();
    }
    unsigned int totValid = suf[0];
    if (totValid >= K) {
        unsigned int excl = suf[t] - seg[t];
        if (excl < K && excl + seg[t] >= K) {
            unsigned int cum = excl;
            for (int b = 63; b >= 0; --b) {
                unsigned int c = h[binaddr((unsigned int)(t * 64 + b))];
                if (cum + c >= K) {
                    params[lev] = (unsigned int)(t * 64 + b);
                    params[8 + lev] = K - cum;
                    params[16 + lev] = 0;
                    break;
                }
                cum += c;
            }
        }
    } else if (t == 0) {
        params[lev] = BIN_NEG;
        params[8 + lev] = 0;
        params[16 + lev] = K - totValid;
    }
}

// ---------------------------------------------------------------- K3
// positional compaction with ballot prefixes; 2 atomics per block max.
__global__ __launch_bounds__(256) void k3_compact(const unsigned int* sbits,
        const unsigned int* clsv, const unsigned int* params,
        const unsigned int* invOff, unsigned long long* finKeys,
        unsigned int* ctrs, unsigned long long* bBuf) {
    int blk = blockIdx.x;
    int t = threadIdx.x;
    int a = blk * 256 + t;
    int lev, idx; lvl_of(a, lev, idx);
    unsigned int sb = sbits[a];
    unsigned int cv = clsv[a];
    unsigned int h16 = sb >> 16;
    unsigned int Bs = params[lev];
    unsigned int rNeg = params[16 + lev];
    unsigned int valid = cv >> 31;
    int lane = t & 63, w = t >> 6;
    unsigned long long lt = (1ull << lane) - 1ull;
    __shared__ unsigned int wInv[4], wFin[4], wB[4];
    __shared__ unsigned int baseFin, baseB;
    unsigned long long mInv = __ballot(valid == 0u);
    if (lane == 0) wInv[w] = (unsigned int)__popcll(mInv);
    __syncthreads();
    unsigned int invRank = invOff[blk] + (unsigned int)__popcll(mInv & lt);
    for (int i = 0; i < w; ++i) invRank += wInv[i];
    bool isFin, isB;
    if (valid) {
        isFin = (h16 > Bs);
        isB   = (h16 == Bs);
    } else {
        isFin = (Bs == BIN_NEG) && (invRank < rNeg);
        isB   = false;
    }
    unsigned long long mFin = __ballot(isFin);
    unsigned long long mB   = __ballot(isB);
    if (lane == 0) { wFin[w] = (unsigned int)__popcll(mFin); wB[w] = (unsigned int)__popcll(mB); }
    __syncthreads();
    if (t == 0) {
        unsigned int tf = wFin[0] + wFin[1] + wFin[2] + wFin[3];
        unsigned int tb = wB[0] + wB[1] + wB[2] + wB[3];
        baseFin = tf ? atomicAdd(&ctrs[0], tf) : 0u;
        baseB   = tb ? atomicAdd(&ctrs[1 + lev], tb) : 0u;
    }
    __syncthreads();
    if (isFin || isB) {
        unsigned int composite = ((unsigned int)lev << 16) | (unsigned int)idx;
        unsigned int inv = (~composite) & 0x7FFFFu;
        unsigned int low = (inv << 13) | (valid << 7) | (cv & 0x7Fu);
        unsigned long long key = ((unsigned long long)sb << 32) | low;
        if (isFin) {
            unsigned int p = baseFin + (unsigned int)__popcll(mFin & lt);
            for (int i = 0; i < w; ++i) p += wFin[i];
            if (p < NF) finKeys[p] = key;
        } else {
            unsigned int p = baseB + (unsigned int)__popcll(mB & lt);
            for (int i = 0; i < w; ++i) p += wB[i];
            if (p < BCAP) bBuf[(size_t)lev * BCAP + p] = key;
        }
    }
}

// ---------------------------------------------------------------- K5
// (k4 fused in) Every block redundantly resolves the per-level boundary
// ties in its own LDS from k3's deterministic bBuf content — same result
// in all blocks, no extra dispatch, no cross-block ordering needed.
// Then rank-by-counting + decode + clip + area/score.
__global__ __launch_bounds__(256) void k5_rank(InPtrs P,
        const unsigned long long* finKeys, const unsigned int* ctrs,
        const unsigned int* params, const unsigned long long* bBuf,
        float4* sBox, float* sScore, unsigned int* sCV, float* sArea) {
    __shared__ unsigned long long keys[NF];
    __shared__ unsigned long long kb[BCAP];
    __shared__ unsigned int rnk[64];
    int t = threadIdx.x;
    unsigned int fc = ctrs[0];
    if (fc > NF) fc = NF;
    for (int i = t; i < (int)fc; i += 256) keys[i] = finKeys[i];
    if (t < 64) rnk[t] = 0;
    __syncthreads();
    unsigned int pos = fc;
    for (int lev = 0; lev < 5; ++lev) {
        unsigned int bc = ctrs[1 + lev];
        int n = (bc > BCAP) ? BCAP : (int)bc;
        int r = (int)params[8 + lev];
        if (r > n) r = n;
        if (r > 0) {
            int m = 1; while (m < n) m <<= 1;
            for (int i = t; i < m; i += 256)
                kb[i] = (i < n) ? bBuf[(size_t)lev * BCAP + i] : 0ull;
            __syncthreads();
            for (int len = 2; len <= m; len <<= 1) {
                for (int st = len >> 1; st > 0; st >>= 1) {
                    for (int i = t; i < m; i += 256) {
                        int j = i ^ st;
                        if (j > i) {
                            unsigned long long a = kb[i], b = kb[j];
                            bool up = ((i & len) == 0);
                            if (up ? (a < b) : (a > b)) { kb[i] = b; kb[j] = a; }
                        }
                    }
                    __syncthreads();
                }
            }
            for (int i = t; i < r; i += 256)
                if (pos + (unsigned int)i < NF) keys[pos + i] = kb[i];
            pos += (unsigned int)r;
            __syncthreads();
        }
    }
    for (int i = (int)pos + t; i < NF; i += 256) keys[i] = (unsigned long long)i;
    __syncthreads();
    int lf = t & 63;
    int seg = t >> 6;
    int f = blockIdx.x * 64 + lf;
    unsigned long long my = (f < NF) ? keys[f] : 0ull;
    if (f < NF) {
        unsigned int c = 0;
        int s0 = seg * 1064, s1 = s0 + 1064;
        for (int i = s0; i < s1; ++i) c += (keys[i] > my) ? 1u : 0u;
        atomicAdd(&rnk[lf], c);
    }
    __syncthreads();
    if (seg == 0 && f < NF) {
        unsigned int r = rnk[lf];
        unsigned int sb  = (unsigned int)(my >> 32);
        unsigned int low = (unsigned int)my;
        unsigned int composite = (~(low >> 13)) & 0x7FFFFu;
        int lev = composite >> 16;
        int idx = composite & 0xFFFF;
        float4 b = ((const float4*)P.reg[lev])[idx];
        float vy1 = P.loc[0], vx1 = P.loc[1], vy2 = P.loc[2], vx2 = P.loc[3];
        float y1 = fmaxf(b.x, vy1), x1 = fmaxf(b.y, vx1);
        float y2 = fminf(b.z, vy2), x2 = fminf(b.w, vx2);
        float area = __fmul_rn(fmaxf(y2 - y1, 0.0f), fmaxf(x2 - x1, 0.0f));
        unsigned int valid = (low >> 7) & 1u;
        sBox[r] = make_float4(y1, x1, y2, x2);
        sScore[r] = valid ? funkey(sb) : 0.0f;
        sCV[r] = (low & 0x7Fu) | (valid << 31);
        sArea[r] = area;
    }
}

// ---------------------------------------------------------------- K6
// sparse adjacency: triangular 1D grid of 64x64 tiles.
__global__ __launch_bounds__(256) void k6_adj(const float4* sBox,
        const float* sArea, unsigned int* cnt, unsigned short* nbr) {
    int L = blockIdx.x;
    float fr = sqrtf(8.0f * (float)L + 1.0f);
    int jt = (int)((fr - 1.0f) * 0.5f);
    while ((jt + 1) * (jt + 2) / 2 <= L) jt++;
    while (jt * (jt + 1) / 2 > L) jt--;
    int it = L - jt * (jt + 1) / 2;
    __shared__ float4 cb[64]; __shared__ float ca[64];
    __shared__ float4 rb[64]; __shared__ float ra[64];
    int t = threadIdx.x;
    if (t < 64) {
        int j = jt * 64 + t;
        if (j < NF) { cb[t] = sBox[j]; ca[t] = sArea[j]; }
        int i = it * 64 + t;
        if (i < NF) { rb[t] = sBox[i]; ra[t] = sArea[i]; }
    }
    __syncthreads();
    int lj = t & 63;
    int j = jt * 64 + lj;
    if (j >= NF) return;
    float4 B = cb[lj]; float ab = ca[lj];
    for (int li = (t >> 6); li < 64; li += 4) {
        int i = it * 64 + li;
        if (i >= j) continue;
        float4 A = rb[li]; float aa = ra[li];
        float iy1 = fmaxf(A.x, B.x), ix1 = fmaxf(A.y, B.y);
        float iy2 = fminf(A.z, B.z), ix2 = fminf(A.w, B.w);
        float ih = fmaxf(iy2 - iy1, 0.0f), iw = fmaxf(ix2 - ix1, 0.0f);
        float inter = __fmul_rn(ih, iw);
        float uni = __fsub_rn(__fadd_rn(aa, ab), inter);
        float iou = __fdiv_rn(inter, fmaxf(uni, 1e-9f));
        if (iou > 0.5f) {
            unsigned int p = atomicAdd(&cnt[j], 1u);
            if (p < CAPD) nbr[(size_t)j * CAPD + p] = (unsigned short)i;
        }
    }
}

// ---------------------------------------------------------------- K7
// CSR into LDS once, 16 all-LDS keep iterations, top-100 emit.
__global__ __launch_bounds__(1024) void k7_nms(InPtrs P, const float4* sBox,
        const float* sScore, const unsigned int* sCV, const unsigned int* cnt,
        const unsigned short* nbr, float* out) {
    __shared__ unsigned char bufA[NF];
    __shared__ unsigned char bufB[NF];
    __shared__ unsigned int csum[1024];
    __shared__ unsigned int off[NF + 1];
    __shared__ unsigned short degs[NF];
    __shared__ unsigned short edges[EC];
    __shared__ float ploc[6];
    int t = threadIdx.x;
    if (t < 6) ploc[t] = P.loc[t];
    for (int j = t; j < NF; j += 1024) {
        unsigned int d = cnt[j]; if (d > CAPD) d = CAPD;
        degs[j] = (unsigned short)d;
        bufA[j] = 1;
    }
    __syncthreads();
    const int CH = 5;
    {
        unsigned int dq[CH]; unsigned int s = 0;
        #pragma unroll
        for (int q = 0; q < CH; ++q) {
            int j = t * CH + q;
            unsigned int d = (j < NF) ? (unsigned int)degs[j] : 0u;
            dq[q] = d; s += d;
        }
        csum[t] = s;
        __syncthreads();
        for (int o = 1; o < 1024; o <<= 1) {
            unsigned int v = csum[t];
            unsigned int add = (t >= o) ? csum[t - o] : 0u;
            __syncthreads();
            csum[t] = v + add;
            __syncthreads();
        }
        unsigned int base = csum[t] - s;
        #pragma unroll
        for (int q = 0; q < CH; ++q) {
            int j = t * CH + q;
            if (j < NF) { off[j] = base; base += dq[q]; }
        }
        if (t == 1023) off[NF] = csum[1023];
    }
    __syncthreads();
    unsigned int E = off[NF];
    bool useLds = (E <= (unsigned int)EC);
    if (useLds) {
        for (int j = t; j < NF; j += 1024) {
            unsigned int o = off[j];
            unsigned int d = degs[j];
            const unsigned short* nl = nbr + (size_t)j * CAPD;
            for (unsigned int e = 0; e < d; ++e) edges[o + e] = nl[e];
        }
    }
    __syncthreads();
    unsigned char* cur = bufA; unsigned char* nxt = bufB;
    for (int itr = 0; itr < NITER; ++itr) {
        if (useLds) {
            for (int j = t; j < NF; j += 1024) {
                unsigned int d = degs[j];
                unsigned int o = off[j];
                unsigned char kp = 1;
                for (unsigned int e = 0; e < d; ++e)
                    if (cur[edges[o + e]]) { kp = 0; break; }
                nxt[j] = kp;
            }
        } else {
            for (int j = t; j < NF; j += 1024) {
                unsigned int d = degs[j];
                const unsigned short* nl = nbr + (size_t)j * CAPD;
                unsigned char kp = 1;
                for (unsigned int e = 0; e < d; ++e)
                    if (cur[nl[e]]) { kp = 0; break; }
                nxt[j] = kp;
            }
        }
        __syncthreads();
        unsigned char* tm = cur; cur = nxt; nxt = tm;
    }
    int base = t * CH;
    unsigned char kf[CH];
    unsigned int sum = 0;
    #pragma unroll
    for (int q = 0; q < CH; ++q) {
        int j = base + q;
        unsigned char v = 0;
        if (j < NF) v = cur[j] & (unsigned char)(sCV[j] >> 31);
        kf[q] = v; sum += v;
    }
    csum[t] = sum;
    __syncthreads();
    for (int o = 1; o < 1024; o <<= 1) {
        unsigned int v = csum[t];
        unsigned int add = (t >= o) ? csum[t - o] : 0u;
        __syncthreads();
        csum[t] = v + add;
        __syncthreads();
    }
    unsigned int keptTot = csum[1023];
    unsigned int run = csum[t] - sum;
    float vy1 = ploc[0], vx1 = ploc[1], vy2 = ploc[2], vx2 = ploc[3];
    float sy = ploc[4] / fmaxf(vy2 - vy1, 1e-6f);
    float sx = ploc[5] / fmaxf(vx2 - vx1, 1e-6f);
    #pragma unroll
    for (int q = 0; q < CH; ++q) {
        int j = base + q;
        if (j >= NF) break;
        unsigned int slot = 0xFFFFFFFFu;
        float sc = 0.0f;
        if (kf[q]) {
            if (run < 100u) { slot = run; sc = sScore[j]; }
            run++;
        } else if (keptTot < 100u) {
            unsigned int nk = (unsigned int)j - run;
            unsigned int s2 = keptTot + nk;
            if (s2 < 100u) { slot = s2; sc = 0.0f; }
        }
        if (slot < 100u) {
            float4 b = sBox[j];
            out[slot * 4 + 0] = (b.x - vy1) * sy;
            out[slot * 4 + 1] = (b.y - vx1) * sx;
            out[slot * 4 + 2] = (b.z - vy1) * sy;
            out[slot * 4 + 3] = (b.w - vx1) * sx;
            out[400 + slot] = (float)(sCV[j] & 0x7Fu);
            out[500 + slot] = sc;
        }
    }
}

extern "C" void kernel_launch(void* const* d_in, const int* in_sizes, int n_in,
                              void* d_out, int out_size, void* d_ws, size_t ws_size,
                              hipStream_t stream) {
    (void)n_in; (void)out_size; (void)ws_size;
    InPtrs P;
    bool inter = (in_sizes[1] == 65536 * 4);
    for (int s = 0; s < 5; ++s) {
        P.cls[s] = (const float*)d_in[inter ? 2 * s : s];
        P.reg[s] = (const float*)d_in[inter ? 2 * s + 1 : 5 + s];
    }
    P.loc = (const float*)d_in[10];

    char* w = (char*)d_ws;
    unsigned int* hist   = (unsigned int*)(w + OFF_HIST);
    unsigned int* cnt    = (unsigned int*)(w + OFF_CNT);
    unsigned int* ctrs   = (unsigned int*)(w + OFF_CTR);
    unsigned int* sbits  = (unsigned int*)(w + OFF_SBITS);
    unsigned int* clsv   = (unsigned int*)(w + OFF_CLSV);
    unsigned int* params = (unsigned int*)(w + OFF_PAR);
    unsigned int* invBlk = (unsigned int*)(w + OFF_INVB);
    unsigned int* invOff = (unsigned int*)(w + OFF_INVO);
    unsigned long long* finKeys = (unsigned long long*)(w + OFF_FINK);
    unsigned long long* bBuf    = (unsigned long long*)(w + OFF_BBUF);
    float4* sBox  = (float4*)(w + OFF_SBOX);
    float* sScore = (float*)(w + OFF_SSC);
    unsigned int* sCV = (unsigned int*)(w + OFF_SCV);
    float* sArea  = (float*)(w + OFF_SAR);
    unsigned short* nbr = (unsigned short*)(w + OFF_NBR);

    hipMemsetAsync(d_ws, 0, ZERO_SZ, stream);
    k1_score<<<NBLK, 1024, 0, stream>>>(P, hist, sbits, clsv, invBlk);
    k2_scan<<<6, 1024, 0, stream>>>(hist, invBlk, params, invOff);
    k3_compact<<<NBLK, 256, 0, stream>>>(sbits, clsv, params, invOff, finKeys, ctrs, bBuf);
    k5_rank<<<67, 256, 0, stream>>>(P, finKeys, ctrs, params, bBuf, sBox, sScore, sCV, sArea);
    k6_adj<<<2278, 256, 0, stream>>>(sBox, sArea, cnt, nbr);
    k7_nms<<<1, 1024, 0, stream>>>(P, sBox, sScore, sCV, cnt, nbr, (float*)d_out);
}

// Round 6
// 196.877 us; speedup vs baseline: 2.3650x; 1.2888x over previous
//
#include <hip/hip_runtime.h>
#include <math.h>

#define NANCH 87296
#define NF 4256        // 1000*4 + 256 finalists
#define CAPD 128       // max neighbors per column
#define NBINS 65536
#define NITER 16       // 15 scan iterations + initial keep
#define BCAP 2048      // boundary-bin buffer per level
#define EC 8192        // LDS edge cap (packed i<<16|j) for k7
#define NBLK 341       // 256-anchor blocks; level boundaries are multiples of 256
#define BIN_NEG 0x407Fu  // fkey(-1.0f) >> 16

struct InPtrs {
    const float* cls[5];
    const float* reg[5];
    const float* loc;
};

// workspace layout
constexpr size_t SZ_HIST  = 5ull * NBINS * 4;
constexpr size_t OFF_HIST = 0;
constexpr size_t OFF_CNT  = OFF_HIST + SZ_HIST;
constexpr size_t OFF_CTR  = OFF_CNT + (size_t)NF * 4;   // [0]=finCount,[1..5]=bCount
constexpr size_t ZERO_SZ  = OFF_CTR + 64;
constexpr size_t OFF_SBITS = ((ZERO_SZ + 255) / 256) * 256;
constexpr size_t OFF_CLSV  = OFF_SBITS + (size_t)NANCH * 4;
constexpr size_t OFF_PAR   = OFF_CLSV + (size_t)NANCH * 4;  // B*[5]@0,r*[5]@8,rNeg[5]@16
constexpr size_t OFF_INVB  = OFF_PAR + 128;                 // per-block invalid counts
constexpr size_t OFF_INVO  = OFF_INVB + (size_t)NBLK * 4;   // scanned offsets
constexpr size_t OFF_FINK  = ((OFF_INVO + (size_t)NBLK * 4 + 255) / 256) * 256;
constexpr size_t OFF_BBUF  = OFF_FINK + (size_t)NF * 8;
constexpr size_t OFF_SBOX  = OFF_BBUF + 5ull * BCAP * 8;
constexpr size_t OFF_SSC   = OFF_SBOX + (size_t)NF * 16;
constexpr size_t OFF_SCV   = OFF_SSC + (size_t)NF * 4;
constexpr size_t OFF_SAR   = OFF_SCV + (size_t)NF * 4;
constexpr size_t OFF_NBR   = OFF_SAR + (size_t)NF * 4;

__device__ __forceinline__ void lvl_of(int a, int& lev, int& idx) {
    if (a < 65536)      { lev = 0; idx = a; }
    else if (a < 81920) { lev = 1; idx = a - 65536; }
    else if (a < 86016) { lev = 2; idx = a - 81920; }
    else if (a < 87040) { lev = 3; idx = a - 86016; }
    else                { lev = 4; idx = a - 87040; }
}

__device__ __forceinline__ unsigned int fkey(float f) {
    unsigned int u = __float_as_uint(f);
    return u ^ ((u & 0x80000000u) ? 0xFFFFFFFFu : 0x80000000u);
}
__device__ __forceinline__ float funkey(unsigned int k) {
    return __uint_as_float(k ^ ((k & 0x80000000u) ? 0x80000000u : 0xFFFFFFFFu));
}
// swizzle: low 6 bin bits -> high address bits. Consecutive (hot) bins land
// 4 KB apart (k1 atomics spread over distinct lines / L2 slices), while a
// 64-bin value-segment c is COLUMN c of a 64x1024 matrix -> k2 sums it with
// lane-coalesced loads h[(q<<10)|c].
__device__ __forceinline__ unsigned int binaddr(unsigned int bin) {
    return ((bin & 63u) << 10) | (bin >> 6);
}

// ---------------------------------------------------------------- K1
// 4 threads/anchor, 256 anchors/block; histogram atomics via binaddr.
__global__ __launch_bounds__(1024) void k1_score(InPtrs P, unsigned int* hist,
        unsigned int* sbits, unsigned int* clsv, unsigned int* invBlk) {
    int t = threadIdx.x;
    int a = blockIdx.x * 256 + (t >> 2);
    int k = t & 3;
    int lev, idx; lvl_of(a, lev, idx);
    const float4* row = (const float4*)(P.cls[lev] + (size_t)idx * 80);
    float best = -INFINITY; int bi = 0;
    #pragma unroll
    for (int q = 0; q < 5; ++q) {
        float4 v = row[q * 4 + k];
        int c0 = q * 16 + k * 4;
        if (v.x > best) { best = v.x; bi = c0 + 0; }
        if (v.y > best) { best = v.y; bi = c0 + 1; }
        if (v.z > best) { best = v.z; bi = c0 + 2; }
        if (v.w > best) { best = v.w; bi = c0 + 3; }
    }
    #pragma unroll
    for (int m = 1; m < 4; m <<= 1) {
        float ob = __shfl_xor(best, m, 64);
        int  obi = __shfl_xor(bi, m, 64);
        if (ob > best || (ob == best && obi < bi)) { best = ob; bi = obi; }
    }
    bool lead = (k == 0);
    unsigned int valid = 0;
    if (lead) {
        float score = 1.0f / (1.0f + expf(-best));
        valid = (score > 0.05f) ? 1u : 0u;
        float psm = valid ? score : -1.0f;
        unsigned int sb = fkey(psm);
        sbits[a] = sb;
        clsv[a] = (unsigned int)(bi + 1) | (valid << 31);
        if (valid) atomicAdd(&hist[(size_t)lev * NBINS + binaddr(sb >> 16)], 1u);
    }
    __shared__ unsigned int wv[16];
    unsigned long long mv = __ballot(lead && valid);
    int lane = t & 63, w = t >> 6;
    if (lane == 0) wv[w] = (unsigned int)__popcll(mv);
    __syncthreads();
    if (t == 0) {
        unsigned int s = 0;
        #pragma unroll
        for (int i = 0; i < 16; ++i) s += wv[i];
        invBlk[blockIdx.x] = 256u - s;
    }
}

// ---------------------------------------------------------------- K2
// blocks 0-4: per-level descending bin scan. Segment sums are column sums
// of the swizzled layout -> coalesced. block 5: invalid-count scan.
__global__ __launch_bounds__(1024) void k2_scan(const unsigned int* hist,
        const unsigned int* invBlk, unsigned int* params, unsigned int* invOff) {
    int t = threadIdx.x;
    if (blockIdx.x == 5) {
        __shared__ unsigned int sv[512];
        __shared__ unsigned int orig[512];
        if (t < 512) {
            unsigned int v = (t < NBLK) ? invBlk[t] : 0u;
            sv[t] = v; orig[t] = v;
        }
        __syncthreads();
        for (int off = 1; off < 512; off <<= 1) {
            unsigned int add = 0;
            if (t < 512 && t >= off) add = sv[t - off];
            __syncthreads();
            if (t < 512) sv[t] += add;
            __syncthreads();
        }
        if (t < NBLK) {
            int segStart = (t < 256) ? 0 : (t < 320) ? 256 : (t < 336) ? 320
                         : (t < 340) ? 336 : 340;
            invOff[t] = sv[t] - orig[t] - (segStart > 0 ? sv[segStart - 1] : 0u);
        }
        return;
    }
    int lev = blockIdx.x;
    unsigned int K = (lev == 4) ? 256u : 1000u;
    const unsigned int* h = hist + (size_t)lev * NBINS;
    __shared__ unsigned int seg[1024];
    __shared__ unsigned int suf[1024];
    unsigned int s = 0;
    #pragma unroll 8
    for (int q = 0; q < 64; ++q) s += h[(q << 10) | t];   // column t, coalesced
    seg[t] = s;
    suf[t] = s;
    __syncthreads();
    for (int off = 1; off < 1024; off <<= 1) {
        unsigned int v = suf[t];
        unsigned int add = (t + off < 1024) ? suf[t + off] : 0u;
        __syncthreads();
        suf[t] = v + add;
        __syncthreads();
    }
    unsigned int totValid = suf[0];
    if (totValid >= K) {
        unsigned int excl = suf[t] - seg[t];
        if (excl < K && excl + seg[t] >= K) {
            unsigned int cum = excl;
            for (int b = 63; b >= 0; --b) {
                unsigned int c = h[(b << 10) | t];
                if (cum + c >= K) {
                    params[lev] = (unsigned int)(t * 64 + b);
                    params[8 + lev] = K - cum;
                    params[16 + lev] = 0;
                    break;
                }
                cum += c;
            }
        }
    } else if (t == 0) {
        params[lev] = BIN_NEG;
        params[8 + lev] = 0;
        params[16 + lev] = K - totValid;
    }
}

// ---------------------------------------------------------------- K3
// positional compaction with ballot prefixes; 2 atomics per block max.
__global__ __launch_bounds__(256) void k3_compact(const unsigned int* sbits,
        const unsigned int* clsv, const unsigned int* params,
        const unsigned int* invOff, unsigned long long* finKeys,
        unsigned int* ctrs, unsigned long long* bBuf) {
    int blk = blockIdx.x;
    int t = threadIdx.x;
    int a = blk * 256 + t;
    int lev, idx; lvl_of(a, lev, idx);
    unsigned int sb = sbits[a];
    unsigned int cv = clsv[a];
    unsigned int h16 = sb >> 16;
    unsigned int Bs = params[lev];
    unsigned int rNeg = params[16 + lev];
    unsigned int valid = cv >> 31;
    int lane = t & 63, w = t >> 6;
    unsigned long long lt = (1ull << lane) - 1ull;
    __shared__ unsigned int wInv[4], wFin[4], wB[4];
    __shared__ unsigned int baseFin, baseB;
    unsigned long long mInv = __ballot(valid == 0u);
    if (lane == 0) wInv[w] = (unsigned int)__popcll(mInv);
    __syncthreads();
    unsigned int invRank = invOff[blk] + (unsigned int)__popcll(mInv & lt);
    for (int i = 0; i < w; ++i) invRank += wInv[i];
    bool isFin, isB;
    if (valid) {
        isFin = (h16 > Bs);
        isB   = (h16 == Bs);
    } else {
        isFin = (Bs == BIN_NEG) && (invRank < rNeg);
        isB   = false;
    }
    unsigned long long mFin = __ballot(isFin);
    unsigned long long mB   = __ballot(isB);
    if (lane == 0) { wFin[w] = (unsigned int)__popcll(mFin); wB[w] = (unsigned int)__popcll(mB); }
    __syncthreads();
    if (t == 0) {
        unsigned int tf = wFin[0] + wFin[1] + wFin[2] + wFin[3];
        unsigned int tb = wB[0] + wB[1] + wB[2] + wB[3];
        baseFin = tf ? atomicAdd(&ctrs[0], tf) : 0u;
        baseB   = tb ? atomicAdd(&ctrs[1 + lev], tb) : 0u;
    }
    __syncthreads();
    if (isFin || isB) {
        unsigned int composite = ((unsigned int)lev << 16) | (unsigned int)idx;
        unsigned int inv = (~composite) & 0x7FFFFu;
        unsigned int low = (inv << 13) | (valid << 7) | (cv & 0x7Fu);
        unsigned long long key = ((unsigned long long)sb << 32) | low;
        if (isFin) {
            unsigned int p = baseFin + (unsigned int)__popcll(mFin & lt);
            for (int i = 0; i < w; ++i) p += wFin[i];
            if (p < NF) finKeys[p] = key;
        } else {
            unsigned int p = baseB + (unsigned int)__popcll(mB & lt);
            for (int i = 0; i < w; ++i) p += wB[i];
            if (p < BCAP) bBuf[(size_t)lev * BCAP + p] = key;
        }
    }
}

// ---------------------------------------------------------------- K5
// (k4 fused) each block redundantly resolves per-level boundary ties in
// LDS, then rank-by-counting + decode + clip + area/score.
__global__ __launch_bounds__(256) void k5_rank(InPtrs P,
        const unsigned long long* finKeys, const unsigned int* ctrs,
        const unsigned int* params, const unsigned long long* bBuf,
        float4* sBox, float* sScore, unsigned int* sCV, float* sArea) {
    __shared__ unsigned long long keys[NF];
    __shared__ unsigned long long kb[BCAP];
    __shared__ unsigned int rnk[64];
    int t = threadIdx.x;
    unsigned int fc = ctrs[0];
    if (fc > NF) fc = NF;
    for (int i = t; i < (int)fc; i += 256) keys[i] = finKeys[i];
    if (t < 64) rnk[t] = 0;
    __syncthreads();
    unsigned int pos = fc;
    for (int lev = 0; lev < 5; ++lev) {
        unsigned int bc = ctrs[1 + lev];
        int n = (bc > BCAP) ? BCAP : (int)bc;
        int r = (int)params[8 + lev];
        if (r > n) r = n;
        if (r > 0) {
            int m = 1; while (m < n) m <<= 1;
            for (int i = t; i < m; i += 256)
                kb[i] = (i < n) ? bBuf[(size_t)lev * BCAP + i] : 0ull;
            __syncthreads();
            for (int len = 2; len <= m; len <<= 1) {
                for (int st = len >> 1; st > 0; st >>= 1) {
                    for (int i = t; i < m; i += 256) {
                        int j = i ^ st;
                        if (j > i) {
                            unsigned long long a = kb[i], b = kb[j];
                            bool up = ((i & len) == 0);
                            if (up ? (a < b) : (a > b)) { kb[i] = b; kb[j] = a; }
                        }
                    }
                    __syncthreads();
                }
            }
            for (int i = t; i < r; i += 256)
                if (pos + (unsigned int)i < NF) keys[pos + i] = kb[i];
            pos += (unsigned int)r;
            __syncthreads();
        }
    }
    for (int i = (int)pos + t; i < NF; i += 256) keys[i] = (unsigned long long)i;
    __syncthreads();
    int lf = t & 63;
    int seg = t >> 6;
    int f = blockIdx.x * 64 + lf;
    unsigned long long my = (f < NF) ? keys[f] : 0ull;
    if (f < NF) {
        unsigned int c = 0;
        int s0 = seg * 1064, s1 = s0 + 1064;
        for (int i = s0; i < s1; ++i) c += (keys[i] > my) ? 1u : 0u;
        atomicAdd(&rnk[lf], c);
    }
    __syncthreads();
    if (seg == 0 && f < NF) {
        unsigned int r = rnk[lf];
        unsigned int sb  = (unsigned int)(my >> 32);
        unsigned int low = (unsigned int)my;
        unsigned int composite = (~(low >> 13)) & 0x7FFFFu;
        int lev = composite >> 16;
        int idx = composite & 0xFFFF;
        float4 b = ((const float4*)P.reg[lev])[idx];
        float vy1 = P.loc[0], vx1 = P.loc[1], vy2 = P.loc[2], vx2 = P.loc[3];
        float y1 = fmaxf(b.x, vy1), x1 = fmaxf(b.y, vx1);
        float y2 = fminf(b.z, vy2), x2 = fminf(b.w, vx2);
        float area = __fmul_rn(fmaxf(y2 - y1, 0.0f), fmaxf(x2 - x1, 0.0f));
        unsigned int valid = (low >> 7) & 1u;
        sBox[r] = make_float4(y1, x1, y2, x2);
        sScore[r] = valid ? funkey(sb) : 0.0f;
        sCV[r] = (low & 0x7Fu) | (valid << 31);
        sArea[r] = area;
    }
}

// ---------------------------------------------------------------- K6
// sparse adjacency: triangular 1D grid of 64x64 tiles.
__global__ __launch_bounds__(256) void k6_adj(const float4* sBox,
        const float* sArea, unsigned int* cnt, unsigned short* nbr) {
    int L = blockIdx.x;
    float fr = sqrtf(8.0f * (float)L + 1.0f);
    int jt = (int)((fr - 1.0f) * 0.5f);
    while ((jt + 1) * (jt + 2) / 2 <= L) jt++;
    while (jt * (jt + 1) / 2 > L) jt--;
    int it = L - jt * (jt + 1) / 2;
    __shared__ float4 cb[64]; __shared__ float ca[64];
    __shared__ float4 rb[64]; __shared__ float ra[64];
    int t = threadIdx.x;
    if (t < 64) {
        int j = jt * 64 + t;
        if (j < NF) { cb[t] = sBox[j]; ca[t] = sArea[j]; }
        int i = it * 64 + t;
        if (i < NF) { rb[t] = sBox[i]; ra[t] = sArea[i]; }
    }
    __syncthreads();
    int lj = t & 63;
    int j = jt * 64 + lj;
    if (j >= NF) return;
    float4 B = cb[lj]; float ab = ca[lj];
    for (int li = (t >> 6); li < 64; li += 4) {
        int i = it * 64 + li;
        if (i >= j) continue;
        float4 A = rb[li]; float aa = ra[li];
        float iy1 = fmaxf(A.x, B.x), ix1 = fmaxf(A.y, B.y);
        float iy2 = fminf(A.z, B.z), ix2 = fminf(A.w, B.w);
        float ih = fmaxf(iy2 - iy1, 0.0f), iw = fmaxf(ix2 - ix1, 0.0f);
        float inter = __fmul_rn(ih, iw);
        float uni = __fsub_rn(__fadd_rn(aa, ab), inter);
        float iou = __fdiv_rn(inter, fmaxf(uni, 1e-9f));
        if (iou > 0.5f) {
            unsigned int p = atomicAdd(&cnt[j], 1u);
            if (p < CAPD) nbr[(size_t)j * CAPD + p] = (unsigned short)i;
        }
    }
}

// ---------------------------------------------------------------- K7
// EDGE-PARALLEL NMS: pack edges (i<<16|j) into LDS once; each of the 16
// iterations is {nxt=1; for each edge: if cur[i] nxt[j]=0} — no per-column
// serial chain, no max-degree divergence. Fallback to global CSR if E>EC.
__global__ __launch_bounds__(1024) void k7_nms(InPtrs P, const float4* sBox,
        const float* sScore, const unsigned int* sCV, const unsigned int* cnt,
        const unsigned short* nbr, float* out) {
    __shared__ unsigned int off[NF + 1];                 // 17028
    __shared__ unsigned int edges[EC];                   // 32768
    __shared__ __align__(4) unsigned char bufA[NF];      // 4256
    __shared__ __align__(4) unsigned char bufB[NF];      // 4256
    __shared__ unsigned int csum[1024];                  // 4096
    __shared__ float ploc[6];
    int t = threadIdx.x;
    if (t < 6) ploc[t] = P.loc[t];
    const int CH = 5;
    unsigned int dq[CH];
    {
        unsigned int s = 0;
        #pragma unroll
        for (int q = 0; q < CH; ++q) {
            int j = t * CH + q;
            unsigned int d = 0;
            if (j < NF) { d = cnt[j]; if (d > CAPD) d = CAPD; }
            dq[q] = d; s += d;
        }
        csum[t] = s;
        for (int j = t; j < NF; j += 1024) bufA[j] = 1;
        __syncthreads();
        for (int o = 1; o < 1024; o <<= 1) {
            unsigned int v = csum[t];
            unsigned int add = (t >= o) ? csum[t - o] : 0u;
            __syncthreads();
            csum[t] = v + add;
            __syncthreads();
        }
        unsigned int base = csum[t] - s;
        #pragma unroll
        for (int q = 0; q < CH; ++q) {
            int j = t * CH + q;
            if (j < NF) { off[j] = base; base += dq[q]; }
        }
        if (t == 1023) off[NF] = csum[1023];
    }
    __syncthreads();
    unsigned int E = off[NF];
    bool useLds = (E <= (unsigned int)EC);
    if (useLds) {
        #pragma unroll
        for (int q = 0; q < CH; ++q) {
            int j = t * CH + q;
            if (j < NF) {
                unsigned int o = off[j];
                unsigned int d = dq[q];
                const unsigned short* nl = nbr + (size_t)j * CAPD;
                for (unsigned int e = 0; e < d; ++e)
                    edges[o + e] = ((unsigned int)nl[e] << 16) | (unsigned int)j;
            }
        }
    }
    __syncthreads();
    unsigned char* cur = bufA; unsigned char* nxt = bufB;
    if (useLds) {
        for (int itr = 0; itr < NITER; ++itr) {
            if (t < (NF + 3) / 4) ((unsigned int*)nxt)[t] = 0x01010101u;
            __syncthreads();
            for (int e = t; e < (int)E; e += 1024) {
                unsigned int pk = edges[e];
                if (cur[pk >> 16]) nxt[pk & 0xFFFFu] = 0;
            }
            __syncthreads();
            unsigned char* tm = cur; cur = nxt; nxt = tm;
        }
    } else {
        for (int itr = 0; itr < NITER; ++itr) {
            for (int j = t; j < NF; j += 1024) {
                unsigned int d = cnt[j]; if (d > CAPD) d = CAPD;
                const unsigned short* nl = nbr + (size_t)j * CAPD;
                unsigned char kp = 1;
                for (unsigned int e = 0; e < d; ++e)
                    if (cur[nl[e]]) { kp = 0; break; }
                nxt[j] = kp;
            }
            __syncthreads();
            unsigned char* tm = cur; cur = nxt; nxt = tm;
        }
    }
    // final keep & emit
    int base = t * CH;
    unsigned char kf[CH];
    unsigned int sum = 0;
    #pragma unroll
    for (int q = 0; q < CH; ++q) {
        int j = base + q;
        unsigned char v = 0;
        if (j < NF) v = cur[j] & (unsigned char)(sCV[j] >> 31);
        kf[q] = v; sum += v;
    }
    csum[t] = sum;
    __syncthreads();
    for (int o = 1; o < 1024; o <<= 1) {
        unsigned int v = csum[t];
        unsigned int add = (t >= o) ? csum[t - o] : 0u;
        __syncthreads();
        csum[t] = v + add;
        __syncthreads();
    }
    unsigned int keptTot = csum[1023];
    unsigned int run = csum[t] - sum;
    float vy1 = ploc[0], vx1 = ploc[1], vy2 = ploc[2], vx2 = ploc[3];
    float sy = ploc[4] / fmaxf(vy2 - vy1, 1e-6f);
    float sx = ploc[5] / fmaxf(vx2 - vx1, 1e-6f);
    #pragma unroll
    for (int q = 0; q < CH; ++q) {
        int j = base + q;
        if (j >= NF) break;
        unsigned int slot = 0xFFFFFFFFu;
        float sc = 0.0f;
        if (kf[q]) {
            if (run < 100u) { slot = run; sc = sScore[j]; }
            run++;
        } else if (keptTot < 100u) {
            unsigned int nk = (unsigned int)j - run;
            unsigned int s2 = keptTot + nk;
            if (s2 < 100u) { slot = s2; sc = 0.0f; }
        }
        if (slot < 100u) {
            float4 b = sBox[j];
            out[slot * 4 + 0] = (b.x - vy1) * sy;
            out[slot * 4 + 1] = (b.y - vx1) * sx;
            out[slot * 4 + 2] = (b.z - vy1) * sy;
            out[slot * 4 + 3] = (b.w - vx1) * sx;
            out[400 + slot] = (float)(sCV[j] & 0x7Fu);
            out[500 + slot] = sc;
        }
    }
}

extern "C" void kernel_launch(void* const* d_in, const int* in_sizes, int n_in,
                              void* d_out, int out_size, void* d_ws, size_t ws_size,
                              hipStream_t stream) {
    (void)n_in; (void)out_size; (void)ws_size;
    InPtrs P;
    bool inter = (in_sizes[1] == 65536 * 4);
    for (int s = 0; s < 5; ++s) {
        P.cls[s] = (const float*)d_in[inter ? 2 * s : s];
        P.reg[s] = (const float*)d_in[inter ? 2 * s + 1 : 5 + s];
    }
    P.loc = (const float*)d_in[10];

    char* w = (char*)d_ws;
    unsigned int* hist   = (unsigned int*)(w + OFF_HIST);
    unsigned int* cnt    = (unsigned int*)(w + OFF_CNT);
    unsigned int* ctrs   = (unsigned int*)(w + OFF_CTR);
    unsigned int* sbits  = (unsigned int*)(w + OFF_SBITS);
    unsigned int* clsv   = (unsigned int*)(w + OFF_CLSV);
    unsigned int* params = (unsigned int*)(w + OFF_PAR);
    unsigned int* invBlk = (unsigned int*)(w + OFF_INVB);
    unsigned int* invOff = (unsigned int*)(w + OFF_INVO);
    unsigned long long* finKeys = (unsigned long long*)(w + OFF_FINK);
    unsigned long long* bBuf    = (unsigned long long*)(w + OFF_BBUF);
    float4* sBox  = (float4*)(w + OFF_SBOX);
    float* sScore = (float*)(w + OFF_SSC);
    unsigned int* sCV = (unsigned int*)(w + OFF_SCV);
    float* sArea  = (float*)(w + OFF_SAR);
    unsigned short* nbr = (unsigned short*)(w + OFF_NBR);

    hipMemsetAsync(d_ws, 0, ZERO_SZ, stream);
    k1_score<<<NBLK, 1024, 0, stream>>>(P, hist, sbits, clsv, invBlk);
    k2_scan<<<6, 1024, 0, stream>>>(hist, invBlk, params, invOff);
    k3_compact<<<NBLK, 256, 0, stream>>>(sbits, clsv, params, invOff, finKeys, ctrs, bBuf);
    k5_rank<<<67, 256, 0, stream>>>(P, finKeys, ctrs, params, bBuf, sBox, sScore, sCV, sArea);
    k6_adj<<<2278, 256, 0, stream>>>(sBox, sArea, cnt, nbr);
    k7_nms<<<1, 1024, 0, stream>>>(P, sBox, sScore, sCV, cnt, nbr, (float*)d_out);
}

// Round 7
// 187.692 us; speedup vs baseline: 2.4807x; 1.0489x over previous
//
#include <hip/hip_runtime.h>
#include <math.h>

#define NANCH 87296
#define NF 4256        // 1000*4 + 256 finalists
#define CAPD 128       // max neighbors per column
#define NBINS 65536
#define NITER 16       // 15 scan iterations + initial keep
#define BCAP 2048      // boundary-bin buffer per level
#define EC 8192        // LDS edge cap (packed i<<16|j) for k7
#define NBLK 341       // 256-anchor blocks; level boundaries are multiples of 256
#define BIN_NEG 0x407Fu  // fkey(-1.0f) >> 16

struct InPtrs {
    const float* cls[5];
    const float* reg[5];
    const float* loc;
};

// workspace layout
constexpr size_t SZ_HIST  = 5ull * NBINS * 4;
constexpr size_t OFF_HIST = 0;
constexpr size_t OFF_CNT  = OFF_HIST + SZ_HIST;
constexpr size_t OFF_CTR  = OFF_CNT + (size_t)NF * 4;   // [0]=finCount,[1..5]=bCount
constexpr size_t ZERO_SZ  = OFF_CTR + 64;
constexpr size_t OFF_SBITS = ((ZERO_SZ + 255) / 256) * 256;
constexpr size_t OFF_CLSV  = OFF_SBITS + (size_t)NANCH * 4;
constexpr size_t OFF_PAR   = OFF_CLSV + (size_t)NANCH * 4;  // B*[5]@0,r*[5]@8,rNeg[5]@16
constexpr size_t OFF_INVB  = OFF_PAR + 128;                 // per-block invalid counts
constexpr size_t OFF_INVO  = OFF_INVB + (size_t)NBLK * 4;   // scanned offsets
constexpr size_t OFF_FINK  = ((OFF_INVO + (size_t)NBLK * 4 + 255) / 256) * 256;
constexpr size_t OFF_BBUF  = OFF_FINK + (size_t)NF * 8;
constexpr size_t OFF_SBOX  = OFF_BBUF + 5ull * BCAP * 8;
constexpr size_t OFF_SSC   = OFF_SBOX + (size_t)NF * 16;
constexpr size_t OFF_SCV   = OFF_SSC + (size_t)NF * 4;
constexpr size_t OFF_SAR   = OFF_SCV + (size_t)NF * 4;
constexpr size_t OFF_NBR   = OFF_SAR + (size_t)NF * 4;

__device__ __forceinline__ void lvl_of(int a, int& lev, int& idx) {
    if (a < 65536)      { lev = 0; idx = a; }
    else if (a < 81920) { lev = 1; idx = a - 65536; }
    else if (a < 86016) { lev = 2; idx = a - 81920; }
    else if (a < 87040) { lev = 3; idx = a - 86016; }
    else                { lev = 4; idx = a - 87040; }
}

__device__ __forceinline__ unsigned int fkey(float f) {
    unsigned int u = __float_as_uint(f);
    return u ^ ((u & 0x80000000u) ? 0xFFFFFFFFu : 0x80000000u);
}
__device__ __forceinline__ float funkey(unsigned int k) {
    return __uint_as_float(k ^ ((k & 0x80000000u) ? 0x80000000u : 0xFFFFFFFFu));
}
// swizzle: low 6 bin bits -> high address bits (hot-bin atomic spread for k1,
// column-coalesced segment sums for k2).
__device__ __forceinline__ unsigned int binaddr(unsigned int bin) {
    return ((bin & 63u) << 10) | (bin >> 6);
}

// ---------------------------------------------------------------- K1
__global__ __launch_bounds__(1024) void k1_score(InPtrs P, unsigned int* hist,
        unsigned int* sbits, unsigned int* clsv, unsigned int* invBlk) {
    int t = threadIdx.x;
    int a = blockIdx.x * 256 + (t >> 2);
    int k = t & 3;
    int lev, idx; lvl_of(a, lev, idx);
    const float4* row = (const float4*)(P.cls[lev] + (size_t)idx * 80);
    float best = -INFINITY; int bi = 0;
    #pragma unroll
    for (int q = 0; q < 5; ++q) {
        float4 v = row[q * 4 + k];
        int c0 = q * 16 + k * 4;
        if (v.x > best) { best = v.x; bi = c0 + 0; }
        if (v.y > best) { best = v.y; bi = c0 + 1; }
        if (v.z > best) { best = v.z; bi = c0 + 2; }
        if (v.w > best) { best = v.w; bi = c0 + 3; }
    }
    #pragma unroll
    for (int m = 1; m < 4; m <<= 1) {
        float ob = __shfl_xor(best, m, 64);
        int  obi = __shfl_xor(bi, m, 64);
        if (ob > best || (ob == best && obi < bi)) { best = ob; bi = obi; }
    }
    bool lead = (k == 0);
    unsigned int valid = 0;
    if (lead) {
        float score = 1.0f / (1.0f + expf(-best));
        valid = (score > 0.05f) ? 1u : 0u;
        float psm = valid ? score : -1.0f;
        unsigned int sb = fkey(psm);
        sbits[a] = sb;
        clsv[a] = (unsigned int)(bi + 1) | (valid << 31);
        if (valid) atomicAdd(&hist[(size_t)lev * NBINS + binaddr(sb >> 16)], 1u);
    }
    __shared__ unsigned int wv[16];
    unsigned long long mv = __ballot(lead && valid);
    int lane = t & 63, w = t >> 6;
    if (lane == 0) wv[w] = (unsigned int)__popcll(mv);
    __syncthreads();
    if (t == 0) {
        unsigned int s = 0;
        #pragma unroll
        for (int i = 0; i < 16; ++i) s += wv[i];
        invBlk[blockIdx.x] = 256u - s;
    }
}

// ---------------------------------------------------------------- K2
__global__ __launch_bounds__(1024) void k2_scan(const unsigned int* hist,
        const unsigned int* invBlk, unsigned int* params, unsigned int* invOff) {
    int t = threadIdx.x;
    if (blockIdx.x == 5) {
        __shared__ unsigned int sv[512];
        __shared__ unsigned int orig[512];
        if (t < 512) {
            unsigned int v = (t < NBLK) ? invBlk[t] : 0u;
            sv[t] = v; orig[t] = v;
        }
        __syncthreads();
        for (int off = 1; off < 512; off <<= 1) {
            unsigned int add = 0;
            if (t < 512 && t >= off) add = sv[t - off];
            __syncthreads();
            if (t < 512) sv[t] += add;
            __syncthreads();
        }
        if (t < NBLK) {
            int segStart = (t < 256) ? 0 : (t < 320) ? 256 : (t < 336) ? 320
                         : (t < 340) ? 336 : 340;
            invOff[t] = sv[t] - orig[t] - (segStart > 0 ? sv[segStart - 1] : 0u);
        }
        return;
    }
    int lev = blockIdx.x;
    unsigned int K = (lev == 4) ? 256u : 1000u;
    const unsigned int* h = hist + (size_t)lev * NBINS;
    __shared__ unsigned int seg[1024];
    __shared__ unsigned int suf[1024];
    unsigned int s = 0;
    #pragma unroll 8
    for (int q = 0; q < 64; ++q) s += h[(q << 10) | t];   // column t, coalesced
    seg[t] = s;
    suf[t] = s;
    __syncthreads();
    for (int off = 1; off < 1024; off <<= 1) {
        unsigned int v = suf[t];
        unsigned int add = (t + off < 1024) ? suf[t + off] : 0u;
        __syncthreads();
        suf[t] = v + add;
        __syncthreads();
    }
    unsigned int totValid = suf[0];
    if (totValid >= K) {
        unsigned int excl = suf[t] - seg[t];
        if (excl < K && excl + seg[t] >= K) {
            unsigned int cum = excl;
            for (int b = 63; b >= 0; --b) {
                unsigned int c = h[(b << 10) | t];
                if (cum + c >= K) {
                    params[lev] = (unsigned int)(t * 64 + b);
                    params[8 + lev] = K - cum;
                    params[16 + lev] = 0;
                    break;
                }
                cum += c;
            }
        }
    } else if (t == 0) {
        params[lev] = BIN_NEG;
        params[8 + lev] = 0;
        params[16 + lev] = K - totValid;
    }
}

// ---------------------------------------------------------------- K3
__global__ __launch_bounds__(256) void k3_compact(const unsigned int* sbits,
        const unsigned int* clsv, const unsigned int* params,
        const unsigned int* invOff, unsigned long long* finKeys,
        unsigned int* ctrs, unsigned long long* bBuf) {
    int blk = blockIdx.x;
    int t = threadIdx.x;
    int a = blk * 256 + t;
    int lev, idx; lvl_of(a, lev, idx);
    unsigned int sb = sbits[a];
    unsigned int cv = clsv[a];
    unsigned int h16 = sb >> 16;
    unsigned int Bs = params[lev];
    unsigned int rNeg = params[16 + lev];
    unsigned int valid = cv >> 31;
    int lane = t & 63, w = t >> 6;
    unsigned long long lt = (1ull << lane) - 1ull;
    __shared__ unsigned int wInv[4], wFin[4], wB[4];
    __shared__ unsigned int baseFin, baseB;
    unsigned long long mInv = __ballot(valid == 0u);
    if (lane == 0) wInv[w] = (unsigned int)__popcll(mInv);
    __syncthreads();
    unsigned int invRank = invOff[blk] + (unsigned int)__popcll(mInv & lt);
    for (int i = 0; i < w; ++i) invRank += wInv[i];
    bool isFin, isB;
    if (valid) {
        isFin = (h16 > Bs);
        isB   = (h16 == Bs);
    } else {
        isFin = (Bs == BIN_NEG) && (invRank < rNeg);
        isB   = false;
    }
    unsigned long long mFin = __ballot(isFin);
    unsigned long long mB   = __ballot(isB);
    if (lane == 0) { wFin[w] = (unsigned int)__popcll(mFin); wB[w] = (unsigned int)__popcll(mB); }
    __syncthreads();
    if (t == 0) {
        unsigned int tf = wFin[0] + wFin[1] + wFin[2] + wFin[3];
        unsigned int tb = wB[0] + wB[1] + wB[2] + wB[3];
        baseFin = tf ? atomicAdd(&ctrs[0], tf) : 0u;
        baseB   = tb ? atomicAdd(&ctrs[1 + lev], tb) : 0u;
    }
    __syncthreads();
    if (isFin || isB) {
        unsigned int composite = ((unsigned int)lev << 16) | (unsigned int)idx;
        unsigned int inv = (~composite) & 0x7FFFFu;
        unsigned int low = (inv << 13) | (valid << 7) | (cv & 0x7Fu);
        unsigned long long key = ((unsigned long long)sb << 32) | low;
        if (isFin) {
            unsigned int p = baseFin + (unsigned int)__popcll(mFin & lt);
            for (int i = 0; i < w; ++i) p += wFin[i];
            if (p < NF) finKeys[p] = key;
        } else {
            unsigned int p = baseB + (unsigned int)__popcll(mB & lt);
            for (int i = 0; i < w; ++i) p += wB[i];
            if (p < BCAP) bBuf[(size_t)lev * BCAP + p] = key;
        }
    }
}

// ---------------------------------------------------------------- K5
// Boundary ties resolved by COUNTING-FILTER (keep kb[i] iff fewer than r
// greater keys — keys unique so exactly r survive; order in keys[] is
// irrelevant because ranks are comparison-counted afterwards). Rank loop
// vectorized: ds_read_b128 (2 keys) x unroll 4 -> latency amortized.
__global__ __launch_bounds__(256) void k5_rank(InPtrs P,
        const unsigned long long* finKeys, const unsigned int* ctrs,
        const unsigned int* params, const unsigned long long* bBuf,
        float4* sBox, float* sScore, unsigned int* sCV, float* sArea) {
    __shared__ __align__(16) unsigned long long keys[NF];
    __shared__ __align__(16) unsigned long long kb[BCAP];
    __shared__ unsigned int rnk[64];
    __shared__ unsigned int posS;
    int t = threadIdx.x;
    unsigned int fc = ctrs[0];
    if (fc > NF) fc = NF;
    for (int i = t; i < (int)fc; i += 256) keys[i] = finKeys[i];
    if (t < 64) rnk[t] = 0;
    if (t == 0) posS = fc;
    __syncthreads();
    for (int lev = 0; lev < 5; ++lev) {
        unsigned int bc = ctrs[1 + lev];
        int n = (bc > BCAP) ? BCAP : (int)bc;
        int r = (int)params[8 + lev];
        if (r > n) r = n;
        if (r > 0) {
            for (int i = t; i < n; i += 256) kb[i] = bBuf[(size_t)lev * BCAP + i];
            __syncthreads();
            for (int i = t; i < n; i += 256) {
                unsigned long long my = kb[i];
                unsigned int c = 0;
                #pragma unroll 4
                for (int j = 0; j < n; ++j) c += (kb[j] > my) ? 1u : 0u;
                if (c < (unsigned int)r) {
                    unsigned int p = atomicAdd(&posS, 1u);
                    if (p < NF) keys[p] = my;
                }
            }
            __syncthreads();
        }
    }
    unsigned int pos = posS;
    for (int i = (int)pos + t; i < NF; i += 256) keys[i] = (unsigned long long)i;
    __syncthreads();
    int lf = t & 63;
    int seg = t >> 6;
    int f = blockIdx.x * 64 + lf;
    unsigned long long my = (f < NF) ? keys[f] : ~0ull;
    {
        unsigned int c = 0;
        const ulonglong2* kp = (const ulonglong2*)keys + seg * 532;  // 1064 keys
        #pragma unroll 4
        for (int i = 0; i < 532; ++i) {
            ulonglong2 v = kp[i];
            c += (v.x > my) ? 1u : 0u;
            c += (v.y > my) ? 1u : 0u;
        }
        atomicAdd(&rnk[lf], c);
    }
    __syncthreads();
    if (seg == 0 && f < NF) {
        unsigned int r = rnk[lf];
        unsigned int sb  = (unsigned int)(my >> 32);
        unsigned int low = (unsigned int)my;
        unsigned int composite = (~(low >> 13)) & 0x7FFFFu;
        int lev = composite >> 16;
        int idx = composite & 0xFFFF;
        float4 b = ((const float4*)P.reg[lev])[idx];
        float vy1 = P.loc[0], vx1 = P.loc[1], vy2 = P.loc[2], vx2 = P.loc[3];
        float y1 = fmaxf(b.x, vy1), x1 = fmaxf(b.y, vx1);
        float y2 = fminf(b.z, vy2), x2 = fminf(b.w, vx2);
        float area = __fmul_rn(fmaxf(y2 - y1, 0.0f), fmaxf(x2 - x1, 0.0f));
        unsigned int valid = (low >> 7) & 1u;
        sBox[r] = make_float4(y1, x1, y2, x2);
        sScore[r] = valid ? funkey(sb) : 0.0f;
        sCV[r] = (low & 0x7Fu) | (valid << 31);
        sArea[r] = area;
    }
}

// ---------------------------------------------------------------- K6
__global__ __launch_bounds__(256) void k6_adj(const float4* sBox,
        const float* sArea, unsigned int* cnt, unsigned short* nbr) {
    int L = blockIdx.x;
    float fr = sqrtf(8.0f * (float)L + 1.0f);
    int jt = (int)((fr - 1.0f) * 0.5f);
    while ((jt + 1) * (jt + 2) / 2 <= L) jt++;
    while (jt * (jt + 1) / 2 > L) jt--;
    int it = L - jt * (jt + 1) / 2;
    __shared__ float4 cb[64]; __shared__ float ca[64];
    __shared__ float4 rb[64]; __shared__ float ra[64];
    int t = threadIdx.x;
    if (t < 64) {
        int j = jt * 64 + t;
        if (j < NF) { cb[t] = sBox[j]; ca[t] = sArea[j]; }
        int i = it * 64 + t;
        if (i < NF) { rb[t] = sBox[i]; ra[t] = sArea[i]; }
    }
    __syncthreads();
    int lj = t & 63;
    int j = jt * 64 + lj;
    if (j >= NF) return;
    float4 B = cb[lj]; float ab = ca[lj];
    for (int li = (t >> 6); li < 64; li += 4) {
        int i = it * 64 + li;
        if (i >= j) continue;
        float4 A = rb[li]; float aa = ra[li];
        float iy1 = fmaxf(A.x, B.x), ix1 = fmaxf(A.y, B.y);
        float iy2 = fminf(A.z, B.z), ix2 = fminf(A.w, B.w);
        float ih = fmaxf(iy2 - iy1, 0.0f), iw = fmaxf(ix2 - ix1, 0.0f);
        float inter = __fmul_rn(ih, iw);
        float uni = __fsub_rn(__fadd_rn(aa, ab), inter);
        float iou = __fdiv_rn(inter, fmaxf(uni, 1e-9f));
        if (iou > 0.5f) {
            unsigned int p = atomicAdd(&cnt[j], 1u);
            if (p < CAPD) nbr[(size_t)j * CAPD + p] = (unsigned short)i;
        }
    }
}

// ---------------------------------------------------------------- K7
__global__ __launch_bounds__(1024) void k7_nms(InPtrs P, const float4* sBox,
        const float* sScore, const unsigned int* sCV, const unsigned int* cnt,
        const unsigned short* nbr, float* out) {
    __shared__ unsigned int off[NF + 1];
    __shared__ unsigned int edges[EC];
    __shared__ __align__(4) unsigned char bufA[NF];
    __shared__ __align__(4) unsigned char bufB[NF];
    __shared__ unsigned int csum[1024];
    __shared__ float ploc[6];
    int t = threadIdx.x;
    if (t < 6) ploc[t] = P.loc[t];
    const int CH = 5;
    unsigned int dq[CH];
    {
        unsigned int s = 0;
        #pragma unroll
        for (int q = 0; q < CH; ++q) {
            int j = t * CH + q;
            unsigned int d = 0;
            if (j < NF) { d = cnt[j]; if (d > CAPD) d = CAPD; }
            dq[q] = d; s += d;
        }
        csum[t] = s;
        for (int j = t; j < NF; j += 1024) bufA[j] = 1;
        __syncthreads();
        for (int o = 1; o < 1024; o <<= 1) {
            unsigned int v = csum[t];
            unsigned int add = (t >= o) ? csum[t - o] : 0u;
            __syncthreads();
            csum[t] = v + add;
            __syncthreads();
        }
        unsigned int base = csum[t] - s;
        #pragma unroll
        for (int q = 0; q < CH; ++q) {
            int j = t * CH + q;
            if (j < NF) { off[j] = base; base += dq[q]; }
        }
        if (t == 1023) off[NF] = csum[1023];
    }
    __syncthreads();
    unsigned int E = off[NF];
    bool useLds = (E <= (unsigned int)EC);
    if (useLds) {
        #pragma unroll
        for (int q = 0; q < CH; ++q) {
            int j = t * CH + q;
            if (j < NF) {
                unsigned int o = off[j];
                unsigned int d = dq[q];
                const unsigned short* nl = nbr + (size_t)j * CAPD;
                for (unsigned int e = 0; e < d; ++e)
                    edges[o + e] = ((unsigned int)nl[e] << 16) | (unsigned int)j;
            }
        }
    }
    __syncthreads();
    unsigned char* cur = bufA; unsigned char* nxt = bufB;
    if (useLds) {
        for (int itr = 0; itr < NITER; ++itr) {
            if (t < (NF + 3) / 4) ((unsigned int*)nxt)[t] = 0x01010101u;
            __syncthreads();
            for (int e = t; e < (int)E; e += 1024) {
                unsigned int pk = edges[e];
                if (cur[pk >> 16]) nxt[pk & 0xFFFFu] = 0;
            }
            __syncthreads();
            unsigned char* tm = cur; cur = nxt; nxt = tm;
        }
    } else {
        for (int itr = 0; itr < NITER; ++itr) {
            for (int j = t; j < NF; j += 1024) {
                unsigned int d = cnt[j]; if (d > CAPD) d = CAPD;
                const unsigned short* nl = nbr + (size_t)j * CAPD;
                unsigned char kp = 1;
                for (unsigned int e = 0; e < d; ++e)
                    if (cur[nl[e]]) { kp = 0; break; }
                nxt[j] = kp;
            }
            __syncthreads();
            unsigned char* tm = cur; cur = nxt; nxt = tm;
        }
    }
    // final keep & emit
    int base = t * CH;
    unsigned char kf[CH];
    unsigned int sum = 0;
    #pragma unroll
    for (int q = 0; q < CH; ++q) {
        int j = base + q;
        unsigned char v = 0;
        if (j < NF) v = cur[j] & (unsigned char)(sCV[j] >> 31);
        kf[q] = v; sum += v;
    }
    csum[t] = sum;
    __syncthreads();
    for (int o = 1; o < 1024; o <<= 1) {
        unsigned int v = csum[t];
        unsigned int add = (t >= o) ? csum[t - o] : 0u;
        __syncthreads();
        csum[t] = v + add;
        __syncthreads();
    }
    unsigned int keptTot = csum[1023];
    unsigned int run = csum[t] - sum;
    float vy1 = ploc[0], vx1 = ploc[1], vy2 = ploc[2], vx2 = ploc[3];
    float sy = ploc[4] / fmaxf(vy2 - vy1, 1e-6f);
    float sx = ploc[5] / fmaxf(vx2 - vx1, 1e-6f);
    #pragma unroll
    for (int q = 0; q < CH; ++q) {
        int j = base + q;
        if (j >= NF) break;
        unsigned int slot = 0xFFFFFFFFu;
        float sc = 0.0f;
        if (kf[q]) {
            if (run < 100u) { slot = run; sc = sScore[j]; }
            run++;
        } else if (keptTot < 100u) {
            unsigned int nk = (unsigned int)j - run;
            unsigned int s2 = keptTot + nk;
            if (s2 < 100u) { slot = s2; sc = 0.0f; }
        }
        if (slot < 100u) {
            float4 b = sBox[j];
            out[slot * 4 + 0] = (b.x - vy1) * sy;
            out[slot * 4 + 1] = (b.y - vx1) * sx;
            out[slot * 4 + 2] = (b.z - vy1) * sy;
            out[slot * 4 + 3] = (b.w - vx1) * sx;
            out[400 + slot] = (float)(sCV[j] & 0x7Fu);
            out[500 + slot] = sc;
        }
    }
}

extern "C" void kernel_launch(void* const* d_in, const int* in_sizes, int n_in,
                              void* d_out, int out_size, void* d_ws, size_t ws_size,
                              hipStream_t stream) {
    (void)n_in; (void)out_size; (void)ws_size;
    InPtrs P;
    bool inter = (in_sizes[1] == 65536 * 4);
    for (int s = 0; s < 5; ++s) {
        P.cls[s] = (const float*)d_in[inter ? 2 * s : s];
        P.reg[s] = (const float*)d_in[inter ? 2 * s + 1 : 5 + s];
    }
    P.loc = (const float*)d_in[10];

    char* w = (char*)d_ws;
    unsigned int* hist   = (unsigned int*)(w + OFF_HIST);
    unsigned int* cnt    = (unsigned int*)(w + OFF_CNT);
    unsigned int* ctrs   = (unsigned int*)(w + OFF_CTR);
    unsigned int* sbits  = (unsigned int*)(w + OFF_SBITS);
    unsigned int* clsv   = (unsigned int*)(w + OFF_CLSV);
    unsigned int* params = (unsigned int*)(w + OFF_PAR);
    unsigned int* invBlk = (unsigned int*)(w + OFF_INVB);
    unsigned int* invOff = (unsigned int*)(w + OFF_INVO);
    unsigned long long* finKeys = (unsigned long long*)(w + OFF_FINK);
    unsigned long long* bBuf    = (unsigned long long*)(w + OFF_BBUF);
    float4* sBox  = (float4*)(w + OFF_SBOX);
    float* sScore = (float*)(w + OFF_SSC);
    unsigned int* sCV = (unsigned int*)(w + OFF_SCV);
    float* sArea  = (float*)(w + OFF_SAR);
    unsigned short* nbr = (unsigned short*)(w + OFF_NBR);

    hipMemsetAsync(d_ws, 0, ZERO_SZ, stream);
    k1_score<<<NBLK, 1024, 0, stream>>>(P, hist, sbits, clsv, invBlk);
    k2_scan<<<6, 1024, 0, stream>>>(hist, invBlk, params, invOff);
    k3_compact<<<NBLK, 256, 0, stream>>>(sbits, clsv, params, invOff, finKeys, ctrs, bBuf);
    k5_rank<<<67, 256, 0, stream>>>(P, finKeys, ctrs, params, bBuf, sBox, sScore, sCV, sArea);
    k6_adj<<<2278, 256, 0, stream>>>(sBox, sArea, cnt, nbr);
    k7_nms<<<1, 1024, 0, stream>>>(P, sBox, sScore, sCV, cnt, nbr, (float*)d_out);
}

// Round 8
// 185.565 us; speedup vs baseline: 2.5091x; 1.0115x over previous
//
#include <hip/hip_runtime.h>
#include <math.h>

#define NANCH 87296
#define NF 4256        // 1000*4 + 256 finalists
#define CAPD 128       // max neighbors per column
#define NITER 16       // 15 scan iterations + initial keep
#define BCAP 512       // boundary-bin buffer per level (24-bit bins -> ~8 entries)
#define EC 8192        // LDS edge cap (packed i<<16|j) for k7
#define NBLK 341       // 256-anchor blocks; level boundaries are multiples of 256
// 24-bit score bins: valid scores in (0.05, 1.0] -> sb>>8 in [0xBD4C00, 0xBF8000]
#define BIN_BASE 0xBD4C00u
#define NB24 147456    // padded to 1024 threads x 144 bins
#define BPT 144        // bins per k2 thread

struct InPtrs {
    const float* cls[5];
    const float* reg[5];
    const float* loc;
};

// workspace layout
constexpr size_t SZ_HIST  = 5ull * NB24 * 4;            // 2,949,120
constexpr size_t OFF_HIST = 0;
constexpr size_t OFF_CNT  = OFF_HIST + SZ_HIST;
constexpr size_t OFF_CTR  = OFF_CNT + (size_t)NF * 4;   // [0]=finCount,[1..5]=bCount
constexpr size_t ZERO_SZ  = OFF_CTR + 64;
constexpr size_t OFF_SBITS = ((ZERO_SZ + 255) / 256) * 256;
constexpr size_t OFF_CLSV  = OFF_SBITS + (size_t)NANCH * 4;
constexpr size_t OFF_PAR   = OFF_CLSV + (size_t)NANCH * 4;  // B*[5]@0,r*[5]@8,rNeg[5]@16
constexpr size_t OFF_INVB  = OFF_PAR + 128;                 // per-block invalid counts
constexpr size_t OFF_INVO  = OFF_INVB + (size_t)NBLK * 4;   // scanned offsets
constexpr size_t OFF_FINK  = ((OFF_INVO + (size_t)NBLK * 4 + 255) / 256) * 256;
constexpr size_t OFF_BBUF  = OFF_FINK + (size_t)NF * 8;
constexpr size_t OFF_SBOX  = OFF_BBUF + 5ull * BCAP * 8;
constexpr size_t OFF_SSC   = OFF_SBOX + (size_t)NF * 16;
constexpr size_t OFF_SCV   = OFF_SSC + (size_t)NF * 4;
constexpr size_t OFF_SAR   = OFF_SCV + (size_t)NF * 4;
constexpr size_t OFF_NBR   = OFF_SAR + (size_t)NF * 4;

__device__ __forceinline__ void lvl_of(int a, int& lev, int& idx) {
    if (a < 65536)      { lev = 0; idx = a; }
    else if (a < 81920) { lev = 1; idx = a - 65536; }
    else if (a < 86016) { lev = 2; idx = a - 81920; }
    else if (a < 87040) { lev = 3; idx = a - 86016; }
    else                { lev = 4; idx = a - 87040; }
}

__device__ __forceinline__ unsigned int fkey(float f) {
    unsigned int u = __float_as_uint(f);
    return u ^ ((u & 0x80000000u) ? 0xFFFFFFFFu : 0x80000000u);
}
__device__ __forceinline__ float funkey(unsigned int k) {
    return __uint_as_float(k ^ ((k & 0x80000000u) ? 0x80000000u : 0xFFFFFFFFu));
}
// bin value v (= owner*BPT + i) stored at addr i*1024 + owner: k2's segment
// sums are lane-coalesced; atomics spread naturally (~30k touched bins).
__device__ __forceinline__ unsigned int bin24_addr(unsigned int v) {
    unsigned int owner = v / BPT;
    unsigned int i = v - owner * BPT;
    return (i << 10) | owner;
}

// ---------------------------------------------------------------- K1
__global__ __launch_bounds__(1024) void k1_score(InPtrs P, unsigned int* hist,
        unsigned int* sbits, unsigned int* clsv, unsigned int* invBlk) {
    int t = threadIdx.x;
    int a = blockIdx.x * 256 + (t >> 2);
    int k = t & 3;
    int lev, idx; lvl_of(a, lev, idx);
    const float4* row = (const float4*)(P.cls[lev] + (size_t)idx * 80);
    float best = -INFINITY; int bi = 0;
    #pragma unroll
    for (int q = 0; q < 5; ++q) {
        float4 v = row[q * 4 + k];
        int c0 = q * 16 + k * 4;
        if (v.x > best) { best = v.x; bi = c0 + 0; }
        if (v.y > best) { best = v.y; bi = c0 + 1; }
        if (v.z > best) { best = v.z; bi = c0 + 2; }
        if (v.w > best) { best = v.w; bi = c0 + 3; }
    }
    #pragma unroll
    for (int m = 1; m < 4; m <<= 1) {
        float ob = __shfl_xor(best, m, 64);
        int  obi = __shfl_xor(bi, m, 64);
        if (ob > best || (ob == best && obi < bi)) { best = ob; bi = obi; }
    }
    bool lead = (k == 0);
    unsigned int valid = 0;
    if (lead) {
        float score = 1.0f / (1.0f + expf(-best));
        valid = (score > 0.05f) ? 1u : 0u;
        float psm = valid ? score : -1.0f;
        unsigned int sb = fkey(psm);
        sbits[a] = sb;
        clsv[a] = (unsigned int)(bi + 1) | (valid << 31);
        if (valid) {
            unsigned int bin = (sb >> 8) - BIN_BASE;   // in [0xCC, 144384]
            atomicAdd(&hist[(size_t)lev * NB24 + bin24_addr(bin)], 1u);
        }
    }
    __shared__ unsigned int wv[16];
    unsigned long long mv = __ballot(lead && valid);
    int lane = t & 63, w = t >> 6;
    if (lane == 0) wv[w] = (unsigned int)__popcll(mv);
    __syncthreads();
    if (t == 0) {
        unsigned int s = 0;
        #pragma unroll
        for (int i = 0; i < 16; ++i) s += wv[i];
        invBlk[blockIdx.x] = 256u - s;
    }
}

// ---------------------------------------------------------------- K2
// blocks 0-4: per-level descending 24-bit-bin scan. Thread t owns values
// [t*BPT, (t+1)*BPT), loads coalesced at h[i*1024+t].
// B*=0 with rNeg>0 encodes "all valid pass" (valid bins are always > 0).
// block 5: segmented exclusive scan of per-block invalid counts.
__global__ __launch_bounds__(1024) void k2_scan(const unsigned int* hist,
        const unsigned int* invBlk, unsigned int* params, unsigned int* invOff) {
    int t = threadIdx.x;
    if (blockIdx.x == 5) {
        __shared__ unsigned int sv[512];
        __shared__ unsigned int orig[512];
        if (t < 512) {
            unsigned int v = (t < NBLK) ? invBlk[t] : 0u;
            sv[t] = v; orig[t] = v;
        }
        __syncthreads();
        for (int off = 1; off < 512; off <<= 1) {
            unsigned int add = 0;
            if (t < 512 && t >= off) add = sv[t - off];
            __syncthreads();
            if (t < 512) sv[t] += add;
            __syncthreads();
        }
        if (t < NBLK) {
            int segStart = (t < 256) ? 0 : (t < 320) ? 256 : (t < 336) ? 320
                         : (t < 340) ? 336 : 340;
            invOff[t] = sv[t] - orig[t] - (segStart > 0 ? sv[segStart - 1] : 0u);
        }
        return;
    }
    int lev = blockIdx.x;
    unsigned int K = (lev == 4) ? 256u : 1000u;
    const unsigned int* h = hist + (size_t)lev * NB24;
    __shared__ unsigned int seg[1024];
    __shared__ unsigned int suf[1024];
    unsigned int s = 0;
    #pragma unroll 8
    for (int i = 0; i < BPT; ++i) s += h[(i << 10) | t];
    seg[t] = s;
    suf[t] = s;
    __syncthreads();
    for (int off = 1; off < 1024; off <<= 1) {
        unsigned int v = suf[t];
        unsigned int add = (t + off < 1024) ? suf[t + off] : 0u;
        __syncthreads();
        suf[t] = v + add;
        __syncthreads();
    }
    unsigned int totValid = suf[0];
    if (totValid >= K) {
        unsigned int excl = suf[t] - seg[t];
        if (excl < K && excl + seg[t] >= K) {
            unsigned int cum = excl;
            for (int i = BPT - 1; i >= 0; --i) {
                unsigned int c = h[(i << 10) | t];
                if (cum + c >= K) {
                    params[lev] = (unsigned int)(t * BPT + i);
                    params[8 + lev] = K - cum;
                    params[16 + lev] = 0;
                    break;
                }
                cum += c;
            }
        }
    } else if (t == 0) {
        params[lev] = 0;              // all valid pass (valid bins > 0)
        params[8 + lev] = 0;
        params[16 + lev] = K - totValid;
    }
}

// ---------------------------------------------------------------- K3
__global__ __launch_bounds__(256) void k3_compact(const unsigned int* sbits,
        const unsigned int* clsv, const unsigned int* params,
        const unsigned int* invOff, unsigned long long* finKeys,
        unsigned int* ctrs, unsigned long long* bBuf) {
    int blk = blockIdx.x;
    int t = threadIdx.x;
    int a = blk * 256 + t;
    int lev, idx; lvl_of(a, lev, idx);
    unsigned int sb = sbits[a];
    unsigned int cv = clsv[a];
    unsigned int bin = (sb >> 8) - BIN_BASE;   // valid only
    unsigned int Bs = params[lev];
    unsigned int rNeg = params[16 + lev];
    unsigned int valid = cv >> 31;
    int lane = t & 63, w = t >> 6;
    unsigned long long lt = (1ull << lane) - 1ull;
    __shared__ unsigned int wInv[4], wFin[4], wB[4];
    __shared__ unsigned int baseFin, baseB;
    unsigned long long mInv = __ballot(valid == 0u);
    if (lane == 0) wInv[w] = (unsigned int)__popcll(mInv);
    __syncthreads();
    unsigned int invRank = invOff[blk] + (unsigned int)__popcll(mInv & lt);
    for (int i = 0; i < w; ++i) invRank += wInv[i];
    bool isFin, isB;
    if (valid) {
        isFin = (bin > Bs);
        isB   = (bin == Bs);
    } else {
        isFin = (rNeg > 0) && (invRank < rNeg);
        isB   = false;
    }
    unsigned long long mFin = __ballot(isFin);
    unsigned long long mB   = __ballot(isB);
    if (lane == 0) { wFin[w] = (unsigned int)__popcll(mFin); wB[w] = (unsigned int)__popcll(mB); }
    __syncthreads();
    if (t == 0) {
        unsigned int tf = wFin[0] + wFin[1] + wFin[2] + wFin[3];
        unsigned int tb = wB[0] + wB[1] + wB[2] + wB[3];
        baseFin = tf ? atomicAdd(&ctrs[0], tf) : 0u;
        baseB   = tb ? atomicAdd(&ctrs[1 + lev], tb) : 0u;
    }
    __syncthreads();
    if (isFin || isB) {
        unsigned int composite = ((unsigned int)lev << 16) | (unsigned int)idx;
        unsigned int inv = (~composite) & 0x7FFFFu;
        unsigned int low = (inv << 13) | (valid << 7) | (cv & 0x7Fu);
        unsigned long long key = ((unsigned long long)sb << 32) | low;
        if (isFin) {
            unsigned int p = baseFin + (unsigned int)__popcll(mFin & lt);
            for (int i = 0; i < w; ++i) p += wFin[i];
            if (p < NF) finKeys[p] = key;
        } else {
            unsigned int p = baseB + (unsigned int)__popcll(mB & lt);
            for (int i = 0; i < w; ++i) p += wB[i];
            if (p < BCAP) bBuf[(size_t)lev * BCAP + p] = key;
        }
    }
}

// ---------------------------------------------------------------- K5
// Boundary ties now tiny (24-bit bins -> ~8 entries): counting-filter is
// trivial. Rank loop: ds_read_b128 x unroll 4.
__global__ __launch_bounds__(256) void k5_rank(InPtrs P,
        const unsigned long long* finKeys, const unsigned int* ctrs,
        const unsigned int* params, const unsigned long long* bBuf,
        float4* sBox, float* sScore, unsigned int* sCV, float* sArea) {
    __shared__ __align__(16) unsigned long long keys[NF];
    __shared__ __align__(16) unsigned long long kb[BCAP];
    __shared__ unsigned int rnk[64];
    __shared__ unsigned int posS;
    int t = threadIdx.x;
    unsigned int fc = ctrs[0];
    if (fc > NF) fc = NF;
    for (int i = t; i < (int)fc; i += 256) keys[i] = finKeys[i];
    if (t < 64) rnk[t] = 0;
    if (t == 0) posS = fc;
    __syncthreads();
    for (int lev = 0; lev < 5; ++lev) {
        unsigned int bc = ctrs[1 + lev];
        int n = (bc > BCAP) ? BCAP : (int)bc;
        int r = (int)params[8 + lev];
        if (r > n) r = n;
        if (r > 0) {
            for (int i = t; i < n; i += 256) kb[i] = bBuf[(size_t)lev * BCAP + i];
            __syncthreads();
            for (int i = t; i < n; i += 256) {
                unsigned long long my = kb[i];
                unsigned int c = 0;
                for (int j = 0; j < n; ++j) c += (kb[j] > my) ? 1u : 0u;
                if (c < (unsigned int)r) {
                    unsigned int p = atomicAdd(&posS, 1u);
                    if (p < NF) keys[p] = my;
                }
            }
            __syncthreads();
        }
    }
    unsigned int pos = posS;
    for (int i = (int)pos + t; i < NF; i += 256) keys[i] = (unsigned long long)i;
    __syncthreads();
    int lf = t & 63;
    int seg = t >> 6;
    int f = blockIdx.x * 64 + lf;
    unsigned long long my = (f < NF) ? keys[f] : ~0ull;
    {
        unsigned int c = 0;
        const ulonglong2* kp = (const ulonglong2*)keys + seg * 532;  // 1064 keys
        #pragma unroll 4
        for (int i = 0; i < 532; ++i) {
            ulonglong2 v = kp[i];
            c += (v.x > my) ? 1u : 0u;
            c += (v.y > my) ? 1u : 0u;
        }
        atomicAdd(&rnk[lf], c);
    }
    __syncthreads();
    if (seg == 0 && f < NF) {
        unsigned int r = rnk[lf];
        unsigned int sb  = (unsigned int)(my >> 32);
        unsigned int low = (unsigned int)my;
        unsigned int composite = (~(low >> 13)) & 0x7FFFFu;
        int lev = composite >> 16;
        int idx = composite & 0xFFFF;
        float4 b = ((const float4*)P.reg[lev])[idx];
        float vy1 = P.loc[0], vx1 = P.loc[1], vy2 = P.loc[2], vx2 = P.loc[3];
        float y1 = fmaxf(b.x, vy1), x1 = fmaxf(b.y, vx1);
        float y2 = fminf(b.z, vy2), x2 = fminf(b.w, vx2);
        float area = __fmul_rn(fmaxf(y2 - y1, 0.0f), fmaxf(x2 - x1, 0.0f));
        unsigned int valid = (low >> 7) & 1u;
        sBox[r] = make_float4(y1, x1, y2, x2);
        sScore[r] = valid ? funkey(sb) : 0.0f;
        sCV[r] = (low & 0x7Fu) | (valid << 31);
        sArea[r] = area;
    }
}

// ---------------------------------------------------------------- K6
__global__ __launch_bounds__(256) void k6_adj(const float4* sBox,
        const float* sArea, unsigned int* cnt, unsigned short* nbr) {
    int L = blockIdx.x;
    float fr = sqrtf(8.0f * (float)L + 1.0f);
    int jt = (int)((fr - 1.0f) * 0.5f);
    while ((jt + 1) * (jt + 2) / 2 <= L) jt++;
    while (jt * (jt + 1) / 2 > L) jt--;
    int it = L - jt * (jt + 1) / 2;
    __shared__ float4 cb[64]; __shared__ float ca[64];
    __shared__ float4 rb[64]; __shared__ float ra[64];
    int t = threadIdx.x;
    if (t < 64) {
        int j = jt * 64 + t;
        if (j < NF) { cb[t] = sBox[j]; ca[t] = sArea[j]; }
        int i = it * 64 + t;
        if (i < NF) { rb[t] = sBox[i]; ra[t] = sArea[i]; }
    }
    __syncthreads();
    int lj = t & 63;
    int j = jt * 64 + lj;
    if (j >= NF) return;
    float4 B = cb[lj]; float ab = ca[lj];
    for (int li = (t >> 6); li < 64; li += 4) {
        int i = it * 64 + li;
        if (i >= j) continue;
        float4 A = rb[li]; float aa = ra[li];
        float iy1 = fmaxf(A.x, B.x), ix1 = fmaxf(A.y, B.y);
        float iy2 = fminf(A.z, B.z), ix2 = fminf(A.w, B.w);
        float ih = fmaxf(iy2 - iy1, 0.0f), iw = fmaxf(ix2 - ix1, 0.0f);
        float inter = __fmul_rn(ih, iw);
        float uni = __fsub_rn(__fadd_rn(aa, ab), inter);
        float iou = __fdiv_rn(inter, fmaxf(uni, 1e-9f));
        if (iou > 0.5f) {
            unsigned int p = atomicAdd(&cnt[j], 1u);
            if (p < CAPD) nbr[(size_t)j * CAPD + p] = (unsigned short)i;
        }
    }
}

// ---------------------------------------------------------------- K7
__global__ __launch_bounds__(1024) void k7_nms(InPtrs P, const float4* sBox,
        const float* sScore, const unsigned int* sCV, const unsigned int* cnt,
        const unsigned short* nbr, float* out) {
    __shared__ unsigned int off[NF + 1];
    __shared__ unsigned int edges[EC];
    __shared__ __align__(4) unsigned char bufA[NF];
    __shared__ __align__(4) unsigned char bufB[NF];
    __shared__ unsigned int csum[1024];
    __shared__ float ploc[6];
    int t = threadIdx.x;
    if (t < 6) ploc[t] = P.loc[t];
    const int CH = 5;
    unsigned int dq[CH];
    {
        unsigned int s = 0;
        #pragma unroll
        for (int q = 0; q < CH; ++q) {
            int j = t * CH + q;
            unsigned int d = 0;
            if (j < NF) { d = cnt[j]; if (d > CAPD) d = CAPD; }
            dq[q] = d; s += d;
        }
        csum[t] = s;
        for (int j = t; j < NF; j += 1024) bufA[j] = 1;
        __syncthreads();
        for (int o = 1; o < 1024; o <<= 1) {
            unsigned int v = csum[t];
            unsigned int add = (t >= o) ? csum[t - o] : 0u;
            __syncthreads();
            csum[t] = v + add;
            __syncthreads();
        }
        unsigned int base = csum[t] - s;
        #pragma unroll
        for (int q = 0; q < CH; ++q) {
            int j = t * CH + q;
            if (j < NF) { off[j] = base; base += dq[q]; }
        }
        if (t == 1023) off[NF] = csum[1023];
    }
    __syncthreads();
    unsigned int E = off[NF];
    bool useLds = (E <= (unsigned int)EC);
    if (useLds) {
        #pragma unroll
        for (int q = 0; q < CH; ++q) {
            int j = t * CH + q;
            if (j < NF) {
                unsigned int o = off[j];
                unsigned int d = dq[q];
                const unsigned short* nl = nbr + (size_t)j * CAPD;
                for (unsigned int e = 0; e < d; ++e)
                    edges[o + e] = ((unsigned int)nl[e] << 16) | (unsigned int)j;
            }
        }
    }
    __syncthreads();
    unsigned char* cur = bufA; unsigned char* nxt = bufB;
    if (useLds) {
        for (int itr = 0; itr < NITER; ++itr) {
            if (t < (NF + 3) / 4) ((unsigned int*)nxt)[t] = 0x01010101u;
            __syncthreads();
            for (int e = t; e < (int)E; e += 1024) {
                unsigned int pk = edges[e];
                if (cur[pk >> 16]) nxt[pk & 0xFFFFu] = 0;
            }
            __syncthreads();
            unsigned char* tm = cur; cur = nxt; nxt = tm;
        }
    } else {
        for (int itr = 0; itr < NITER; ++itr) {
            for (int j = t; j < NF; j += 1024) {
                unsigned int d = cnt[j]; if (d > CAPD) d = CAPD;
                const unsigned short* nl = nbr + (size_t)j * CAPD;
                unsigned char kp = 1;
                for (unsigned int e = 0; e < d; ++e)
                    if (cur[nl[e]]) { kp = 0; break; }
                nxt[j] = kp;
            }
            __syncthreads();
            unsigned char* tm = cur; cur = nxt; nxt = tm;
        }
    }
    // final keep & emit
    int base = t * CH;
    unsigned char kf[CH];
    unsigned int sum = 0;
    #pragma unroll
    for (int q = 0; q < CH; ++q) {
        int j = base + q;
        unsigned char v = 0;
        if (j < NF) v = cur[j] & (unsigned char)(sCV[j] >> 31);
        kf[q] = v; sum += v;
    }
    csum[t] = sum;
    __syncthreads();
    for (int o = 1; o < 1024; o <<= 1) {
        unsigned int v = csum[t];
        unsigned int add = (t >= o) ? csum[t - o] : 0u;
        __syncthreads();
        csum[t] = v + add;
        __syncthreads();
    }
    unsigned int keptTot = csum[1023];
    unsigned int run = csum[t] - sum;
    float vy1 = ploc[0], vx1 = ploc[1], vy2 = ploc[2], vx2 = ploc[3];
    float sy = ploc[4] / fmaxf(vy2 - vy1, 1e-6f);
    float sx = ploc[5] / fmaxf(vx2 - vx1, 1e-6f);
    #pragma unroll
    for (int q = 0; q < CH; ++q) {
        int j = base + q;
        if (j >= NF) break;
        unsigned int slot = 0xFFFFFFFFu;
        float sc = 0.0f;
        if (kf[q]) {
            if (run < 100u) { slot = run; sc = sScore[j]; }
            run++;
        } else if (keptTot < 100u) {
            unsigned int nk = (unsigned int)j - run;
            unsigned int s2 = keptTot + nk;
            if (s2 < 100u) { slot = s2; sc = 0.0f; }
        }
        if (slot < 100u) {
            float4 b = sBox[j];
            out[slot * 4 + 0] = (b.x - vy1) * sy;
            out[slot * 4 + 1] = (b.y - vx1) * sx;
            out[slot * 4 + 2] = (b.z - vy1) * sy;
            out[slot * 4 + 3] = (b.w - vx1) * sx;
            out[400 + slot] = (float)(sCV[j] & 0x7Fu);
            out[500 + slot] = sc;
        }
    }
}

extern "C" void kernel_launch(void* const* d_in, const int* in_sizes, int n_in,
                              void* d_out, int out_size, void* d_ws, size_t ws_size,
                              hipStream_t stream) {
    (void)n_in; (void)out_size; (void)ws_size;
    InPtrs P;
    bool inter = (in_sizes[1] == 65536 * 4);
    for (int s = 0; s < 5; ++s) {
        P.cls[s] = (const float*)d_in[inter ? 2 * s : s];
        P.reg[s] = (const float*)d_in[inter ? 2 * s + 1 : 5 + s];
    }
    P.loc = (const float*)d_in[10];

    char* w = (char*)d_ws;
    unsigned int* hist   = (unsigned int*)(w + OFF_HIST);
    unsigned int* cnt    = (unsigned int*)(w + OFF_CNT);
    unsigned int* ctrs   = (unsigned int*)(w + OFF_CTR);
    unsigned int* sbits  = (unsigned int*)(w + OFF_SBITS);
    unsigned int* clsv   = (unsigned int*)(w + OFF_CLSV);
    unsigned int* params = (unsigned int*)(w + OFF_PAR);
    unsigned int* invBlk = (unsigned int*)(w + OFF_INVB);
    unsigned int* invOff = (unsigned int*)(w + OFF_INVO);
    unsigned long long* finKeys = (unsigned long long*)(w + OFF_FINK);
    unsigned long long* bBuf    = (unsigned long long*)(w + OFF_BBUF);
    float4* sBox  = (float4*)(w + OFF_SBOX);
    float* sScore = (float*)(w + OFF_SSC);
    unsigned int* sCV = (unsigned int*)(w + OFF_SCV);
    float* sArea  = (float*)(w + OFF_SAR);
    unsigned short* nbr = (unsigned short*)(w + OFF_NBR);

    hipMemsetAsync(d_ws, 0, ZERO_SZ, stream);
    k1_score<<<NBLK, 1024, 0, stream>>>(P, hist, sbits, clsv, invBlk);
    k2_scan<<<6, 1024, 0, stream>>>(hist, invBlk, params, invOff);
    k3_compact<<<NBLK, 256, 0, stream>>>(sbits, clsv, params, invOff, finKeys, ctrs, bBuf);
    k5_rank<<<67, 256, 0, stream>>>(P, finKeys, ctrs, params, bBuf, sBox, sScore, sCV, sArea);
    k6_adj<<<2278, 256, 0, stream>>>(sBox, sArea, cnt, nbr);
    k7_nms<<<1, 1024, 0, stream>>>(P, sBox, sScore, sCV, cnt, nbr, (float*)d_out);
}

// Round 9
// 175.844 us; speedup vs baseline: 2.6479x; 1.0553x over previous
//
#include <hip/hip_runtime.h>
#include <math.h>

#define NANCH 87296
#define NF 4256        // 1000*4 + 256 finalists
#define CAPD 128       // max neighbors per column
#define NITER 16       // 15 scan iterations + initial keep
#define BCAP 512       // boundary-bin buffer per level (20-bit bins -> ~3 entries)
#define EC 8192        // LDS edge cap (packed i<<16|j) for k7
#define NBLK 341       // 256-anchor blocks; level boundaries are multiples of 256
// 20-bit score bins: valid scores in (0.05, 1.0] -> sb>>12 in [0xBD4CC, 0xBF800]
#define BASE20 0xBD4CCu
#define NB20 9216      // padded to 1024 threads x 9 bins
#define BPT 9          // bins per k2 thread

struct InPtrs {
    const float* cls[5];
    const float* reg[5];
    const float* loc;
};

// workspace layout
constexpr size_t SZ_HIST  = 5ull * NB20 * 4;            // 184,320
constexpr size_t OFF_HIST = 0;
constexpr size_t OFF_CNT  = OFF_HIST + SZ_HIST;
constexpr size_t OFF_CTR  = OFF_CNT + (size_t)NF * 4;   // [0]=finCount,[1..5]=bCount
constexpr size_t ZERO_SZ  = OFF_CTR + 64;
constexpr size_t OFF_SBITS = ((ZERO_SZ + 255) / 256) * 256;
constexpr size_t OFF_CLSV  = OFF_SBITS + (size_t)NANCH * 4;
constexpr size_t OFF_PAR   = OFF_CLSV + (size_t)NANCH * 4;  // B*[5]@0,r*[5]@8,rNeg[5]@16
constexpr size_t OFF_INVB  = OFF_PAR + 128;                 // per-block invalid counts
constexpr size_t OFF_INVO  = OFF_INVB + (size_t)NBLK * 4;   // scanned offsets
constexpr size_t OFF_FINK  = ((OFF_INVO + (size_t)NBLK * 4 + 255) / 256) * 256;
constexpr size_t OFF_BBUF  = OFF_FINK + (size_t)NF * 8;
constexpr size_t OFF_SBOX  = OFF_BBUF + 5ull * BCAP * 8;
constexpr size_t OFF_SSC   = OFF_SBOX + (size_t)NF * 16;
constexpr size_t OFF_SCV   = OFF_SSC + (size_t)NF * 4;
constexpr size_t OFF_SAR   = OFF_SCV + (size_t)NF * 4;
constexpr size_t OFF_NBR   = OFF_SAR + (size_t)NF * 4;

__device__ __forceinline__ void lvl_of(int a, int& lev, int& idx) {
    if (a < 65536)      { lev = 0; idx = a; }
    else if (a < 81920) { lev = 1; idx = a - 65536; }
    else if (a < 86016) { lev = 2; idx = a - 81920; }
    else if (a < 87040) { lev = 3; idx = a - 86016; }
    else                { lev = 4; idx = a - 87040; }
}

__device__ __forceinline__ unsigned int fkey(float f) {
    unsigned int u = __float_as_uint(f);
    return u ^ ((u & 0x80000000u) ? 0xFFFFFFFFu : 0x80000000u);
}
__device__ __forceinline__ float funkey(unsigned int k) {
    return __uint_as_float(k ^ ((k & 0x80000000u) ? 0x80000000u : 0xFFFFFFFFu));
}
// bin value v = owner*BPT + i, stored at addr i*1024 + owner: k2's segment
// sums are lane-coalesced; k1 atomics spread over ~2k distinct lines.
__device__ __forceinline__ unsigned int bin20_addr(unsigned int v) {
    unsigned int owner = v / BPT;
    unsigned int i = v - owner * BPT;
    return (i << 10) | owner;
}

// ---------------------------------------------------------------- K1
__global__ __launch_bounds__(1024) void k1_score(InPtrs P, unsigned int* hist,
        unsigned int* sbits, unsigned int* clsv, unsigned int* invBlk) {
    int t = threadIdx.x;
    int a = blockIdx.x * 256 + (t >> 2);
    int k = t & 3;
    int lev, idx; lvl_of(a, lev, idx);
    const float4* row = (const float4*)(P.cls[lev] + (size_t)idx * 80);
    float best = -INFINITY; int bi = 0;
    #pragma unroll
    for (int q = 0; q < 5; ++q) {
        float4 v = row[q * 4 + k];
        int c0 = q * 16 + k * 4;
        if (v.x > best) { best = v.x; bi = c0 + 0; }
        if (v.y > best) { best = v.y; bi = c0 + 1; }
        if (v.z > best) { best = v.z; bi = c0 + 2; }
        if (v.w > best) { best = v.w; bi = c0 + 3; }
    }
    #pragma unroll
    for (int m = 1; m < 4; m <<= 1) {
        float ob = __shfl_xor(best, m, 64);
        int  obi = __shfl_xor(bi, m, 64);
        if (ob > best || (ob == best && obi < bi)) { best = ob; bi = obi; }
    }
    bool lead = (k == 0);
    unsigned int valid = 0;
    if (lead) {
        float score = 1.0f / (1.0f + expf(-best));
        valid = (score > 0.05f) ? 1u : 0u;
        float psm = valid ? score : -1.0f;
        unsigned int sb = fkey(psm);
        sbits[a] = sb;
        clsv[a] = (unsigned int)(bi + 1) | (valid << 31);
        if (valid) {
            unsigned int bin = (sb >> 12) - BASE20;   // in [0, 9012]
            atomicAdd(&hist[(size_t)lev * NB20 + bin20_addr(bin)], 1u);
        }
    }
    __shared__ unsigned int wv[16];
    unsigned long long mv = __ballot(lead && valid);
    int lane = t & 63, w = t >> 6;
    if (lane == 0) wv[w] = (unsigned int)__popcll(mv);
    __syncthreads();
    if (t == 0) {
        unsigned int s = 0;
        #pragma unroll
        for (int i = 0; i < 16; ++i) s += wv[i];
        invBlk[blockIdx.x] = 256u - s;
    }
}

// ---------------------------------------------------------------- K2
// blocks 0-4: per-level descending 20-bit-bin scan (thread t owns values
// [t*9, t*9+9), loads coalesced at h[i*1024+t] — 36 KB per block).
// block 5: segmented exclusive scan of per-block invalid counts.
__global__ __launch_bounds__(1024) void k2_scan(const unsigned int* hist,
        const unsigned int* invBlk, unsigned int* params, unsigned int* invOff) {
    int t = threadIdx.x;
    if (blockIdx.x == 5) {
        __shared__ unsigned int sv[512];
        __shared__ unsigned int orig[512];
        if (t < 512) {
            unsigned int v = (t < NBLK) ? invBlk[t] : 0u;
            sv[t] = v; orig[t] = v;
        }
        __syncthreads();
        for (int off = 1; off < 512; off <<= 1) {
            unsigned int add = 0;
            if (t < 512 && t >= off) add = sv[t - off];
            __syncthreads();
            if (t < 512) sv[t] += add;
            __syncthreads();
        }
        if (t < NBLK) {
            int segStart = (t < 256) ? 0 : (t < 320) ? 256 : (t < 336) ? 320
                         : (t < 340) ? 336 : 340;
            invOff[t] = sv[t] - orig[t] - (segStart > 0 ? sv[segStart - 1] : 0u);
        }
        return;
    }
    int lev = blockIdx.x;
    unsigned int K = (lev == 4) ? 256u : 1000u;
    const unsigned int* h = hist + (size_t)lev * NB20;
    __shared__ unsigned int seg[1024];
    __shared__ unsigned int suf[1024];
    unsigned int hc[BPT];
    unsigned int s = 0;
    #pragma unroll
    for (int i = 0; i < BPT; ++i) { hc[i] = h[(i << 10) | t]; s += hc[i]; }
    seg[t] = s;
    suf[t] = s;
    __syncthreads();
    for (int off = 1; off < 1024; off <<= 1) {
        unsigned int v = suf[t];
        unsigned int add = (t + off < 1024) ? suf[t + off] : 0u;
        __syncthreads();
        suf[t] = v + add;
        __syncthreads();
    }
    unsigned int totValid = suf[0];
    if (totValid >= K) {
        unsigned int excl = suf[t] - seg[t];
        if (excl < K && excl + seg[t] >= K) {
            unsigned int cum = excl;
            for (int i = BPT - 1; i >= 0; --i) {
                unsigned int c = hc[i];
                if (cum + c >= K) {
                    params[lev] = (unsigned int)(t * BPT + i);
                    params[8 + lev] = K - cum;
                    params[16 + lev] = 0;
                    break;
                }
                cum += c;
            }
        }
    } else if (t == 0) {
        params[lev] = 0;              // all valid pass (valid bins > 0)
        params[8 + lev] = 0;
        params[16 + lev] = K - totValid;
    }
}

// ---------------------------------------------------------------- K3
__global__ __launch_bounds__(256) void k3_compact(const unsigned int* sbits,
        const unsigned int* clsv, const unsigned int* params,
        const unsigned int* invOff, unsigned long long* finKeys,
        unsigned int* ctrs, unsigned long long* bBuf) {
    int blk = blockIdx.x;
    int t = threadIdx.x;
    int a = blk * 256 + t;
    int lev, idx; lvl_of(a, lev, idx);
    unsigned int sb = sbits[a];
    unsigned int cv = clsv[a];
    unsigned int bin = (sb >> 12) - BASE20;   // meaningful for valid only
    unsigned int Bs = params[lev];
    unsigned int rNeg = params[16 + lev];
    unsigned int valid = cv >> 31;
    int lane = t & 63, w = t >> 6;
    unsigned long long lt = (1ull << lane) - 1ull;
    __shared__ unsigned int wInv[4], wFin[4], wB[4];
    __shared__ unsigned int baseFin, baseB;
    unsigned long long mInv = __ballot(valid == 0u);
    if (lane == 0) wInv[w] = (unsigned int)__popcll(mInv);
    __syncthreads();
    unsigned int invRank = invOff[blk] + (unsigned int)__popcll(mInv & lt);
    for (int i = 0; i < w; ++i) invRank += wInv[i];
    bool isFin, isB;
    if (valid) {
        isFin = (bin > Bs);
        isB   = (bin == Bs);
    } else {
        isFin = (rNeg > 0) && (invRank < rNeg);
        isB   = false;
    }
    unsigned long long mFin = __ballot(isFin);
    unsigned long long mB   = __ballot(isB);
    if (lane == 0) { wFin[w] = (unsigned int)__popcll(mFin); wB[w] = (unsigned int)__popcll(mB); }
    __syncthreads();
    if (t == 0) {
        unsigned int tf = wFin[0] + wFin[1] + wFin[2] + wFin[3];
        unsigned int tb = wB[0] + wB[1] + wB[2] + wB[3];
        baseFin = tf ? atomicAdd(&ctrs[0], tf) : 0u;
        baseB   = tb ? atomicAdd(&ctrs[1 + lev], tb) : 0u;
    }
    __syncthreads();
    if (isFin || isB) {
        unsigned int composite = ((unsigned int)lev << 16) | (unsigned int)idx;
        unsigned int inv = (~composite) & 0x7FFFFu;
        unsigned int low = (inv << 13) | (valid << 7) | (cv & 0x7Fu);
        unsigned long long key = ((unsigned long long)sb << 32) | low;
        if (isFin) {
            unsigned int p = baseFin + (unsigned int)__popcll(mFin & lt);
            for (int i = 0; i < w; ++i) p += wFin[i];
            if (p < NF) finKeys[p] = key;
        } else {
            unsigned int p = baseB + (unsigned int)__popcll(mB & lt);
            for (int i = 0; i < w; ++i) p += wB[i];
            if (p < BCAP) bBuf[(size_t)lev * BCAP + p] = key;
        }
    }
}

// ---------------------------------------------------------------- K5
// 266 blocks x 16 finalists: 16 segs x 266 keys -> 133 b128 reads/thread,
// all 256 CUs participate (was 67 blocks x 532 reads/thread).
__global__ __launch_bounds__(256) void k5_rank(InPtrs P,
        const unsigned long long* finKeys, const unsigned int* ctrs,
        const unsigned int* params, const unsigned long long* bBuf,
        float4* sBox, float* sScore, unsigned int* sCV, float* sArea) {
    __shared__ __align__(16) unsigned long long keys[NF];
    __shared__ __align__(16) unsigned long long kb[BCAP];
    __shared__ unsigned int rnk[16];
    __shared__ unsigned int posS;
    int t = threadIdx.x;
    unsigned int fc = ctrs[0];
    if (fc > NF) fc = NF;
    for (int i = t; i < (int)fc; i += 256) keys[i] = finKeys[i];
    if (t < 16) rnk[t] = 0;
    if (t == 0) posS = fc;
    __syncthreads();
    for (int lev = 0; lev < 5; ++lev) {
        unsigned int bc = ctrs[1 + lev];
        int n = (bc > BCAP) ? BCAP : (int)bc;
        int r = (int)params[8 + lev];
        if (r > n) r = n;
        if (r > 0) {
            for (int i = t; i < n; i += 256) kb[i] = bBuf[(size_t)lev * BCAP + i];
            __syncthreads();
            for (int i = t; i < n; i += 256) {
                unsigned long long my = kb[i];
                unsigned int c = 0;
                for (int j = 0; j < n; ++j) c += (kb[j] > my) ? 1u : 0u;
                if (c < (unsigned int)r) {
                    unsigned int p = atomicAdd(&posS, 1u);
                    if (p < NF) keys[p] = my;
                }
            }
            __syncthreads();
        }
    }
    unsigned int pos = posS;
    for (int i = (int)pos + t; i < NF; i += 256) keys[i] = (unsigned long long)i;
    __syncthreads();
    int lf = t & 15;
    int seg = t >> 4;                       // 16 segments of 266 keys
    int f = blockIdx.x * 16 + lf;           // 266*16 = 4256 exactly
    unsigned long long my = keys[f];
    {
        unsigned int c = 0;
        const ulonglong2* kp = (const ulonglong2*)keys + seg * 133;
        #pragma unroll 4
        for (int i = 0; i < 133; ++i) {
            ulonglong2 v = kp[i];
            c += (v.x > my) ? 1u : 0u;
            c += (v.y > my) ? 1u : 0u;
        }
        atomicAdd(&rnk[lf], c);
    }
    __syncthreads();
    if (seg == 0) {
        unsigned int r = rnk[lf];
        unsigned int sb  = (unsigned int)(my >> 32);
        unsigned int low = (unsigned int)my;
        unsigned int composite = (~(low >> 13)) & 0x7FFFFu;
        int lev = composite >> 16;
        int idx = composite & 0xFFFF;
        float4 b = ((const float4*)P.reg[lev])[idx];
        float vy1 = P.loc[0], vx1 = P.loc[1], vy2 = P.loc[2], vx2 = P.loc[3];
        float y1 = fmaxf(b.x, vy1), x1 = fmaxf(b.y, vx1);
        float y2 = fminf(b.z, vy2), x2 = fminf(b.w, vx2);
        float area = __fmul_rn(fmaxf(y2 - y1, 0.0f), fmaxf(x2 - x1, 0.0f));
        unsigned int valid = (low >> 7) & 1u;
        sBox[r] = make_float4(y1, x1, y2, x2);
        sScore[r] = valid ? funkey(sb) : 0.0f;
        sCV[r] = (low & 0x7Fu) | (valid << 31);
        sArea[r] = area;
    }
}

// ---------------------------------------------------------------- K6
__global__ __launch_bounds__(256) void k6_adj(const float4* sBox,
        const float* sArea, unsigned int* cnt, unsigned short* nbr) {
    int L = blockIdx.x;
    float fr = sqrtf(8.0f * (float)L + 1.0f);
    int jt = (int)((fr - 1.0f) * 0.5f);
    while ((jt + 1) * (jt + 2) / 2 <= L) jt++;
    while (jt * (jt + 1) / 2 > L) jt--;
    int it = L - jt * (jt + 1) / 2;
    __shared__ float4 cb[64]; __shared__ float ca[64];
    __shared__ float4 rb[64]; __shared__ float ra[64];
    int t = threadIdx.x;
    if (t < 64) {
        int j = jt * 64 + t;
        if (j < NF) { cb[t] = sBox[j]; ca[t] = sArea[j]; }
        int i = it * 64 + t;
        if (i < NF) { rb[t] = sBox[i]; ra[t] = sArea[i]; }
    }
    __syncthreads();
    int lj = t & 63;
    int j = jt * 64 + lj;
    if (j >= NF) return;
    float4 B = cb[lj]; float ab = ca[lj];
    for (int li = (t >> 6); li < 64; li += 4) {
        int i = it * 64 + li;
        if (i >= j) continue;
        float4 A = rb[li]; float aa = ra[li];
        float iy1 = fmaxf(A.x, B.x), ix1 = fmaxf(A.y, B.y);
        float iy2 = fminf(A.z, B.z), ix2 = fminf(A.w, B.w);
        float ih = fmaxf(iy2 - iy1, 0.0f), iw = fmaxf(ix2 - ix1, 0.0f);
        float inter = __fmul_rn(ih, iw);
        float uni = __fsub_rn(__fadd_rn(aa, ab), inter);
        float iou = __fdiv_rn(inter, fmaxf(uni, 1e-9f));
        if (iou > 0.5f) {
            unsigned int p = atomicAdd(&cnt[j], 1u);
            if (p < CAPD) nbr[(size_t)j * CAPD + p] = (unsigned short)i;
        }
    }
}

// ---------------------------------------------------------------- K7
__global__ __launch_bounds__(1024) void k7_nms(InPtrs P, const float4* sBox,
        const float* sScore, const unsigned int* sCV, const unsigned int* cnt,
        const unsigned short* nbr, float* out) {
    __shared__ unsigned int off[NF + 1];
    __shared__ unsigned int edges[EC];
    __shared__ __align__(4) unsigned char bufA[NF];
    __shared__ __align__(4) unsigned char bufB[NF];
    __shared__ unsigned int csum[1024];
    __shared__ float ploc[6];
    int t = threadIdx.x;
    if (t < 6) ploc[t] = P.loc[t];
    const int CH = 5;
    unsigned int dq[CH];
    {
        unsigned int s = 0;
        #pragma unroll
        for (int q = 0; q < CH; ++q) {
            int j = t * CH + q;
            unsigned int d = 0;
            if (j < NF) { d = cnt[j]; if (d > CAPD) d = CAPD; }
            dq[q] = d; s += d;
        }
        csum[t] = s;
        for (int j = t; j < NF; j += 1024) bufA[j] = 1;
        __syncthreads();
        for (int o = 1; o < 1024; o <<= 1) {
            unsigned int v = csum[t];
            unsigned int add = (t >= o) ? csum[t - o] : 0u;
            __syncthreads();
            csum[t] = v + add;
            __syncthreads();
        }
        unsigned int base = csum[t] - s;
        #pragma unroll
        for (int q = 0; q < CH; ++q) {
            int j = t * CH + q;
            if (j < NF) { off[j] = base; base += dq[q]; }
        }
        if (t == 1023) off[NF] = csum[1023];
    }
    __syncthreads();
    unsigned int E = off[NF];
    bool useLds = (E <= (unsigned int)EC);
    if (useLds) {
        #pragma unroll
        for (int q = 0; q < CH; ++q) {
            int j = t * CH + q;
            if (j < NF) {
                unsigned int o = off[j];
                unsigned int d = dq[q];
                const unsigned short* nl = nbr + (size_t)j * CAPD;
                for (unsigned int e = 0; e < d; ++e)
                    edges[o + e] = ((unsigned int)nl[e] << 16) | (unsigned int)j;
            }
        }
    }
    __syncthreads();
    unsigned char* cur = bufA; unsigned char* nxt = bufB;
    if (useLds) {
        for (int itr = 0; itr < NITER; ++itr) {
            if (t < (NF + 3) / 4) ((unsigned int*)nxt)[t] = 0x01010101u;
            __syncthreads();
            for (int e = t; e < (int)E; e += 1024) {
                unsigned int pk = edges[e];
                if (cur[pk >> 16]) nxt[pk & 0xFFFFu] = 0;
            }
            __syncthreads();
            unsigned char* tm = cur; cur = nxt; nxt = tm;
        }
    } else {
        for (int itr = 0; itr < NITER; ++itr) {
            for (int j = t; j < NF; j += 1024) {
                unsigned int d = cnt[j]; if (d > CAPD) d = CAPD;
                const unsigned short* nl = nbr + (size_t)j * CAPD;
                unsigned char kp = 1;
                for (unsigned int e = 0; e < d; ++e)
                    if (cur[nl[e]]) { kp = 0; break; }
                nxt[j] = kp;
            }
            __syncthreads();
            unsigned char* tm = cur; cur = nxt; nxt = tm;
        }
    }
    // final keep & emit
    int base = t * CH;
    unsigned char kf[CH];
    unsigned int sum = 0;
    #pragma unroll
    for (int q = 0; q < CH; ++q) {
        int j = base + q;
        unsigned char v = 0;
        if (j < NF) v = cur[j] & (unsigned char)(sCV[j] >> 31);
        kf[q] = v; sum += v;
    }
    csum[t] = sum;
    __syncthreads();
    for (int o = 1; o < 1024; o <<= 1) {
        unsigned int v = csum[t];
        unsigned int add = (t >= o) ? csum[t - o] : 0u;
        __syncthreads();
        csum[t] = v + add;
        __syncthreads();
    }
    unsigned int keptTot = csum[1023];
    unsigned int run = csum[t] - sum;
    float vy1 = ploc[0], vx1 = ploc[1], vy2 = ploc[2], vx2 = ploc[3];
    float sy = ploc[4] / fmaxf(vy2 - vy1, 1e-6f);
    float sx = ploc[5] / fmaxf(vx2 - vx1, 1e-6f);
    #pragma unroll
    for (int q = 0; q < CH; ++q) {
        int j = base + q;
        if (j >= NF) break;
        unsigned int slot = 0xFFFFFFFFu;
        float sc = 0.0f;
        if (kf[q]) {
            if (run < 100u) { slot = run; sc = sScore[j]; }
            run++;
        } else if (keptTot < 100u) {
            unsigned int nk = (unsigned int)j - run;
            unsigned int s2 = keptTot + nk;
            if (s2 < 100u) { slot = s2; sc = 0.0f; }
        }
        if (slot < 100u) {
            float4 b = sBox[j];
            out[slot * 4 + 0] = (b.x - vy1) * sy;
            out[slot * 4 + 1] = (b.y - vx1) * sx;
            out[slot * 4 + 2] = (b.z - vy1) * sy;
            out[slot * 4 + 3] = (b.w - vx1) * sx;
            out[400 + slot] = (float)(sCV[j] & 0x7Fu);
            out[500 + slot] = sc;
        }
    }
}

extern "C" void kernel_launch(void* const* d_in, const int* in_sizes, int n_in,
                              void* d_out, int out_size, void* d_ws, size_t ws_size,
                              hipStream_t stream) {
    (void)n_in; (void)out_size; (void)ws_size;
    InPtrs P;
    bool inter = (in_sizes[1] == 65536 * 4);
    for (int s = 0; s < 5; ++s) {
        P.cls[s] = (const float*)d_in[inter ? 2 * s : s];
        P.reg[s] = (const float*)d_in[inter ? 2 * s + 1 : 5 + s];
    }
    P.loc = (const float*)d_in[10];

    char* w = (char*)d_ws;
    unsigned int* hist   = (unsigned int*)(w + OFF_HIST);
    unsigned int* cnt    = (unsigned int*)(w + OFF_CNT);
    unsigned int* ctrs   = (unsigned int*)(w + OFF_CTR);
    unsigned int* sbits  = (unsigned int*)(w + OFF_SBITS);
    unsigned int* clsv   = (unsigned int*)(w + OFF_CLSV);
    unsigned int* params = (unsigned int*)(w + OFF_PAR);
    unsigned int* invBlk = (unsigned int*)(w + OFF_INVB);
    unsigned int* invOff = (unsigned int*)(w + OFF_INVO);
    unsigned long long* finKeys = (unsigned long long*)(w + OFF_FINK);
    unsigned long long* bBuf    = (unsigned long long*)(w + OFF_BBUF);
    float4* sBox  = (float4*)(w + OFF_SBOX);
    float* sScore = (float*)(w + OFF_SSC);
    unsigned int* sCV = (unsigned int*)(w + OFF_SCV);
    float* sArea  = (float*)(w + OFF_SAR);
    unsigned short* nbr = (unsigned short*)(w + OFF_NBR);

    hipMemsetAsync(d_ws, 0, ZERO_SZ, stream);
    k1_score<<<NBLK, 1024, 0, stream>>>(P, hist, sbits, clsv, invBlk);
    k2_scan<<<6, 1024, 0, stream>>>(hist, invBlk, params, invOff);
    k3_compact<<<NBLK, 256, 0, stream>>>(sbits, clsv, params, invOff, finKeys, ctrs, bBuf);
    k5_rank<<<266, 256, 0, stream>>>(P, finKeys, ctrs, params, bBuf, sBox, sScore, sCV, sArea);
    k6_adj<<<2278, 256, 0, stream>>>(sBox, sArea, cnt, nbr);
    k7_nms<<<1, 1024, 0, stream>>>(P, sBox, sScore, sCV, cnt, nbr, (float*)d_out);
}

// Round 10
// 175.633 us; speedup vs baseline: 2.6510x; 1.0012x over previous
//
#include <hip/hip_runtime.h>
#include <math.h>

#define NANCH 87296
#define NF 4256        // 1000*4 + 256 finalists
#define CAPD 128       // max neighbors per column
#define NITER 16       // 15 scan iterations + initial keep
#define BCAP 512       // boundary-bin buffer per level (20-bit bins -> ~3 entries)
#define EC 8192        // LDS edge cap (packed i<<16|j) for k7
#define NBLK 341       // 256-anchor blocks; level boundaries are multiples of 256
// 20-bit score bins: valid scores in (0.05, 1.0] -> sb>>12 in [0xBD4CC, 0xBF800]
#define BASE20 0xBD4CCu
#define NB20 9216      // padded to 1024 threads x 9 bins
#define BPT 9          // bins per k2 thread

struct InPtrs {
    const float* cls[5];
    const float* reg[5];
    const float* loc;
};

// workspace layout
constexpr size_t SZ_HIST  = 5ull * NB20 * 4;            // 184,320
constexpr size_t OFF_HIST = 0;
constexpr size_t OFF_CNT  = OFF_HIST + SZ_HIST;
constexpr size_t OFF_CTR  = OFF_CNT + (size_t)NF * 4;   // [0]=finCount,[1..5]=bCount
constexpr size_t ZERO_SZ  = OFF_CTR + 64;
constexpr size_t OFF_SBITS = ((ZERO_SZ + 255) / 256) * 256;
constexpr size_t OFF_CLSV  = OFF_SBITS + (size_t)NANCH * 4;
constexpr size_t OFF_PAR   = OFF_CLSV + (size_t)NANCH * 4;  // B*[5]@0,r*[5]@8,rNeg[5]@16
constexpr size_t OFF_INVB  = OFF_PAR + 128;                 // per-block invalid counts
constexpr size_t OFF_INVO  = OFF_INVB + (size_t)NBLK * 4;   // scanned offsets
constexpr size_t OFF_FINK  = ((OFF_INVO + (size_t)NBLK * 4 + 255) / 256) * 256;
constexpr size_t OFF_BBUF  = OFF_FINK + (size_t)NF * 8;
constexpr size_t OFF_SBOX  = OFF_BBUF + 5ull * BCAP * 8;
constexpr size_t OFF_SSC   = OFF_SBOX + (size_t)NF * 16;
constexpr size_t OFF_SCV   = OFF_SSC + (size_t)NF * 4;
constexpr size_t OFF_SAR   = OFF_SCV + (size_t)NF * 4;
constexpr size_t OFF_NBR   = OFF_SAR + (size_t)NF * 4;

__device__ __forceinline__ void lvl_of(int a, int& lev, int& idx) {
    if (a < 65536)      { lev = 0; idx = a; }
    else if (a < 81920) { lev = 1; idx = a - 65536; }
    else if (a < 86016) { lev = 2; idx = a - 81920; }
    else if (a < 87040) { lev = 3; idx = a - 86016; }
    else                { lev = 4; idx = a - 87040; }
}

__device__ __forceinline__ unsigned int fkey(float f) {
    unsigned int u = __float_as_uint(f);
    return u ^ ((u & 0x80000000u) ? 0xFFFFFFFFu : 0x80000000u);
}
__device__ __forceinline__ float funkey(unsigned int k) {
    return __uint_as_float(k ^ ((k & 0x80000000u) ? 0x80000000u : 0xFFFFFFFFu));
}
// bin value v = owner*BPT + i, stored at addr i*1024 + owner: k2's segment
// sums are lane-coalesced; k1 atomics spread over ~2k distinct lines.
__device__ __forceinline__ unsigned int bin20_addr(unsigned int v) {
    unsigned int owner = v / BPT;
    unsigned int i = v - owner * BPT;
    return (i << 10) | owner;
}

// ---------------------------------------------------------------- K1
__global__ __launch_bounds__(1024) void k1_score(InPtrs P, unsigned int* hist,
        unsigned int* sbits, unsigned int* clsv, unsigned int* invBlk) {
    int t = threadIdx.x;
    int a = blockIdx.x * 256 + (t >> 2);
    int k = t & 3;
    int lev, idx; lvl_of(a, lev, idx);
    const float4* row = (const float4*)(P.cls[lev] + (size_t)idx * 80);
    float4 v[5];
    #pragma unroll
    for (int q = 0; q < 5; ++q) v[q] = row[q * 4 + k];   // 5 loads in flight
    float best = -INFINITY; int bi = 0;
    #pragma unroll
    for (int q = 0; q < 5; ++q) {
        int c0 = q * 16 + k * 4;
        if (v[q].x > best) { best = v[q].x; bi = c0 + 0; }
        if (v[q].y > best) { best = v[q].y; bi = c0 + 1; }
        if (v[q].z > best) { best = v[q].z; bi = c0 + 2; }
        if (v[q].w > best) { best = v[q].w; bi = c0 + 3; }
    }
    #pragma unroll
    for (int m = 1; m < 4; m <<= 1) {
        float ob = __shfl_xor(best, m, 64);
        int  obi = __shfl_xor(bi, m, 64);
        if (ob > best || (ob == best && obi < bi)) { best = ob; bi = obi; }
    }
    bool lead = (k == 0);
    unsigned int valid = 0;
    if (lead) {
        float score = 1.0f / (1.0f + expf(-best));
        valid = (score > 0.05f) ? 1u : 0u;
        float psm = valid ? score : -1.0f;
        unsigned int sb = fkey(psm);
        sbits[a] = sb;
        clsv[a] = (unsigned int)(bi + 1) | (valid << 31);
        if (valid) {
            unsigned int bin = (sb >> 12) - BASE20;   // in [0, 9012]
            atomicAdd(&hist[(size_t)lev * NB20 + bin20_addr(bin)], 1u);
        }
    }
    __shared__ unsigned int wv[16];
    unsigned long long mv = __ballot(lead && valid);
    int lane = t & 63, w = t >> 6;
    if (lane == 0) wv[w] = (unsigned int)__popcll(mv);
    __syncthreads();
    if (t == 0) {
        unsigned int s = 0;
        #pragma unroll
        for (int i = 0; i < 16; ++i) s += wv[i];
        invBlk[blockIdx.x] = 256u - s;
    }
}

// ---------------------------------------------------------------- K2
__global__ __launch_bounds__(1024) void k2_scan(const unsigned int* hist,
        const unsigned int* invBlk, unsigned int* params, unsigned int* invOff) {
    int t = threadIdx.x;
    if (blockIdx.x == 5) {
        __shared__ unsigned int sv[512];
        __shared__ unsigned int orig[512];
        if (t < 512) {
            unsigned int v = (t < NBLK) ? invBlk[t] : 0u;
            sv[t] = v; orig[t] = v;
        }
        __syncthreads();
        for (int off = 1; off < 512; off <<= 1) {
            unsigned int add = 0;
            if (t < 512 && t >= off) add = sv[t - off];
            __syncthreads();
            if (t < 512) sv[t] += add;
            __syncthreads();
        }
        if (t < NBLK) {
            int segStart = (t < 256) ? 0 : (t < 320) ? 256 : (t < 336) ? 320
                         : (t < 340) ? 336 : 340;
            invOff[t] = sv[t] - orig[t] - (segStart > 0 ? sv[segStart - 1] : 0u);
        }
        return;
    }
    int lev = blockIdx.x;
    unsigned int K = (lev == 4) ? 256u : 1000u;
    const unsigned int* h = hist + (size_t)lev * NB20;
    __shared__ unsigned int seg[1024];
    __shared__ unsigned int suf[1024];
    unsigned int hc[BPT];
    unsigned int s = 0;
    #pragma unroll
    for (int i = 0; i < BPT; ++i) { hc[i] = h[(i << 10) | t]; s += hc[i]; }
    seg[t] = s;
    suf[t] = s;
    __syncthreads();
    for (int off = 1; off < 1024; off <<= 1) {
        unsigned int v = suf[t];
        unsigned int add = (t + off < 1024) ? suf[t + off] : 0u;
        __syncthreads();
        suf[t] = v + add;
        __syncthreads();
    }
    unsigned int totValid = suf[0];
    if (totValid >= K) {
        unsigned int excl = suf[t] - seg[t];
        if (excl < K && excl + seg[t] >= K) {
            unsigned int cum = excl;
            for (int i = BPT - 1; i >= 0; --i) {
                unsigned int c = hc[i];
                if (cum + c >= K) {
                    params[lev] = (unsigned int)(t * BPT + i);
                    params[8 + lev] = K - cum;
                    params[16 + lev] = 0;
                    break;
                }
                cum += c;
            }
        }
    } else if (t == 0) {
        params[lev] = 0;              // all valid pass (valid bins > 0)
        params[8 + lev] = 0;
        params[16 + lev] = K - totValid;
    }
}

// ---------------------------------------------------------------- K3
__global__ __launch_bounds__(256) void k3_compact(const unsigned int* sbits,
        const unsigned int* clsv, const unsigned int* params,
        const unsigned int* invOff, unsigned long long* finKeys,
        unsigned int* ctrs, unsigned long long* bBuf) {
    int blk = blockIdx.x;
    int t = threadIdx.x;
    int a = blk * 256 + t;
    int lev, idx; lvl_of(a, lev, idx);
    unsigned int sb = sbits[a];
    unsigned int cv = clsv[a];
    unsigned int bin = (sb >> 12) - BASE20;   // meaningful for valid only
    unsigned int Bs = params[lev];
    unsigned int rNeg = params[16 + lev];
    unsigned int valid = cv >> 31;
    int lane = t & 63, w = t >> 6;
    unsigned long long lt = (1ull << lane) - 1ull;
    __shared__ unsigned int wInv[4], wFin[4], wB[4];
    __shared__ unsigned int baseFin, baseB;
    unsigned long long mInv = __ballot(valid == 0u);
    if (lane == 0) wInv[w] = (unsigned int)__popcll(mInv);
    __syncthreads();
    unsigned int invRank = invOff[blk] + (unsigned int)__popcll(mInv & lt);
    for (int i = 0; i < w; ++i) invRank += wInv[i];
    bool isFin, isB;
    if (valid) {
        isFin = (bin > Bs);
        isB   = (bin == Bs);
    } else {
        isFin = (rNeg > 0) && (invRank < rNeg);
        isB   = false;
    }
    unsigned long long mFin = __ballot(isFin);
    unsigned long long mB   = __ballot(isB);
    if (lane == 0) { wFin[w] = (unsigned int)__popcll(mFin); wB[w] = (unsigned int)__popcll(mB); }
    __syncthreads();
    if (t == 0) {
        unsigned int tf = wFin[0] + wFin[1] + wFin[2] + wFin[3];
        unsigned int tb = wB[0] + wB[1] + wB[2] + wB[3];
        baseFin = tf ? atomicAdd(&ctrs[0], tf) : 0u;
        baseB   = tb ? atomicAdd(&ctrs[1 + lev], tb) : 0u;
    }
    __syncthreads();
    if (isFin || isB) {
        unsigned int composite = ((unsigned int)lev << 16) | (unsigned int)idx;
        unsigned int inv = (~composite) & 0x7FFFFu;
        unsigned int low = (inv << 13) | (valid << 7) | (cv & 0x7Fu);
        unsigned long long key = ((unsigned long long)sb << 32) | low;
        if (isFin) {
            unsigned int p = baseFin + (unsigned int)__popcll(mFin & lt);
            for (int i = 0; i < w; ++i) p += wFin[i];
            if (p < NF) finKeys[p] = key;
        } else {
            unsigned int p = baseB + (unsigned int)__popcll(mB & lt);
            for (int i = 0; i < w; ++i) p += wB[i];
            if (p < BCAP) bBuf[(size_t)lev * BCAP + p] = key;
        }
    }
}

// ---------------------------------------------------------------- K5
__global__ __launch_bounds__(256) void k5_rank(InPtrs P,
        const unsigned long long* finKeys, const unsigned int* ctrs,
        const unsigned int* params, const unsigned long long* bBuf,
        float4* sBox, float* sScore, unsigned int* sCV, float* sArea) {
    __shared__ __align__(16) unsigned long long keys[NF];
    __shared__ __align__(16) unsigned long long kb[BCAP];
    __shared__ unsigned int rnk[16];
    __shared__ unsigned int posS;
    int t = threadIdx.x;
    unsigned int fc = ctrs[0];
    if (fc > NF) fc = NF;
    for (int i = t; i < (int)fc; i += 256) keys[i] = finKeys[i];
    if (t < 16) rnk[t] = 0;
    if (t == 0) posS = fc;
    __syncthreads();
    for (int lev = 0; lev < 5; ++lev) {
        unsigned int bc = ctrs[1 + lev];
        int n = (bc > BCAP) ? BCAP : (int)bc;
        int r = (int)params[8 + lev];
        if (r > n) r = n;
        if (r > 0) {
            for (int i = t; i < n; i += 256) kb[i] = bBuf[(size_t)lev * BCAP + i];
            __syncthreads();
            for (int i = t; i < n; i += 256) {
                unsigned long long my = kb[i];
                unsigned int c = 0;
                for (int j = 0; j < n; ++j) c += (kb[j] > my) ? 1u : 0u;
                if (c < (unsigned int)r) {
                    unsigned int p = atomicAdd(&posS, 1u);
                    if (p < NF) keys[p] = my;
                }
            }
            __syncthreads();
        }
    }
    unsigned int pos = posS;
    for (int i = (int)pos + t; i < NF; i += 256) keys[i] = (unsigned long long)i;
    __syncthreads();
    int lf = t & 15;
    int seg = t >> 4;                       // 16 segments of 266 keys
    int f = blockIdx.x * 16 + lf;           // 266*16 = 4256 exactly
    unsigned long long my = keys[f];
    {
        unsigned int c = 0;
        const ulonglong2* kp = (const ulonglong2*)keys + seg * 133;
        #pragma unroll 4
        for (int i = 0; i < 133; ++i) {
            ulonglong2 v = kp[i];
            c += (v.x > my) ? 1u : 0u;
            c += (v.y > my) ? 1u : 0u;
        }
        atomicAdd(&rnk[lf], c);
    }
    __syncthreads();
    if (seg == 0) {
        unsigned int r = rnk[lf];
        unsigned int sb  = (unsigned int)(my >> 32);
        unsigned int low = (unsigned int)my;
        unsigned int composite = (~(low >> 13)) & 0x7FFFFu;
        int lev = composite >> 16;
        int idx = composite & 0xFFFF;
        float4 b = ((const float4*)P.reg[lev])[idx];
        float vy1 = P.loc[0], vx1 = P.loc[1], vy2 = P.loc[2], vx2 = P.loc[3];
        float y1 = fmaxf(b.x, vy1), x1 = fmaxf(b.y, vx1);
        float y2 = fminf(b.z, vy2), x2 = fminf(b.w, vx2);
        float area = __fmul_rn(fmaxf(y2 - y1, 0.0f), fmaxf(x2 - x1, 0.0f));
        unsigned int valid = (low >> 7) & 1u;
        sBox[r] = make_float4(y1, x1, y2, x2);
        sScore[r] = valid ? funkey(sb) : 0.0f;
        sCV[r] = (low & 0x7Fu) | (valid << 31);
        sArea[r] = area;
    }
}

// ---------------------------------------------------------------- K6
__global__ __launch_bounds__(256) void k6_adj(const float4* sBox,
        const float* sArea, unsigned int* cnt, unsigned short* nbr) {
    int L = blockIdx.x;
    float fr = sqrtf(8.0f * (float)L + 1.0f);
    int jt = (int)((fr - 1.0f) * 0.5f);
    while ((jt + 1) * (jt + 2) / 2 <= L) jt++;
    while (jt * (jt + 1) / 2 > L) jt--;
    int it = L - jt * (jt + 1) / 2;
    __shared__ float4 cb[64]; __shared__ float ca[64];
    __shared__ float4 rb[64]; __shared__ float ra[64];
    int t = threadIdx.x;
    if (t < 64) {
        int j = jt * 64 + t;
        if (j < NF) { cb[t] = sBox[j]; ca[t] = sArea[j]; }
        int i = it * 64 + t;
        if (i < NF) { rb[t] = sBox[i]; ra[t] = sArea[i]; }
    }
    __syncthreads();
    int lj = t & 63;
    int j = jt * 64 + lj;
    if (j >= NF) return;
    float4 B = cb[lj]; float ab = ca[lj];
    for (int li = (t >> 6); li < 64; li += 4) {
        int i = it * 64 + li;
        if (i >= j) continue;
        float4 A = rb[li]; float aa = ra[li];
        float iy1 = fmaxf(A.x, B.x), ix1 = fmaxf(A.y, B.y);
        float iy2 = fminf(A.z, B.z), ix2 = fminf(A.w, B.w);
        float ih = fmaxf(iy2 - iy1, 0.0f), iw = fmaxf(ix2 - ix1, 0.0f);
        float inter = __fmul_rn(ih, iw);
        float uni = __fsub_rn(__fadd_rn(aa, ab), inter);
        float iou = __fdiv_rn(inter, fmaxf(uni, 1e-9f));
        if (iou > 0.5f) {
            unsigned int p = atomicAdd(&cnt[j], 1u);
            if (p < CAPD) nbr[(size_t)j * CAPD + p] = (unsigned short)i;
        }
    }
}

// ---------------------------------------------------------------- K7
// Edge-parallel NMS. Prefix sums now use wave shuffles (2 barriers instead
// of 20 each); no off[]/degs[] LDS arrays — each thread stages its own
// columns' edges from its locally-scanned base.
__global__ __launch_bounds__(1024) void k7_nms(InPtrs P, const float4* sBox,
        const float* sScore, const unsigned int* sCV, const unsigned int* cnt,
        const unsigned short* nbr, float* out) {
    __shared__ unsigned int edges[EC];
    __shared__ __align__(4) unsigned char bufA[NF];
    __shared__ __align__(4) unsigned char bufB[NF];
    __shared__ unsigned int wsum[16];
    __shared__ float ploc[6];
    int t = threadIdx.x;
    int lane = t & 63, wid = t >> 6;
    if (t < 6) ploc[t] = P.loc[t];
    const int CH = 5;
    unsigned int dq[CH];
    unsigned int s = 0;
    #pragma unroll
    for (int q = 0; q < CH; ++q) {
        int j = t * CH + q;
        unsigned int d = 0;
        if (j < NF) { d = cnt[j]; if (d > CAPD) d = CAPD; }
        dq[q] = d; s += d;
    }
    // wave inclusive scan of s
    unsigned int sc = s;
    #pragma unroll
    for (int o = 1; o < 64; o <<= 1) {
        unsigned int n = __shfl_up(sc, o, 64);
        if (lane >= o) sc += n;
    }
    if (lane == 63) wsum[wid] = sc;
    if (t < 1064) ((unsigned int*)bufA)[t] = 0x01010101u;   // NF=4256=1064*4
    __syncthreads();
    unsigned int wbase = 0, tot = 0;
    #pragma unroll
    for (int i = 0; i < 16; ++i) {
        unsigned int v = wsum[i];
        if (i < wid) wbase += v;
        tot += v;
    }
    unsigned int E = tot;
    bool useLds = (E <= (unsigned int)EC);
    if (useLds) {
        unsigned int base = wbase + sc - s;   // exclusive prefix
        #pragma unroll
        for (int q = 0; q < CH; ++q) {
            int j = t * CH + q;
            if (j < NF) {
                unsigned int d = dq[q];
                const unsigned short* nl = nbr + (size_t)j * CAPD;
                for (unsigned int e = 0; e < d; ++e)
                    edges[base + e] = ((unsigned int)nl[e] << 16) | (unsigned int)j;
                base += d;
            }
        }
    }
    __syncthreads();
    unsigned char* cur = bufA; unsigned char* nxt = bufB;
    if (useLds) {
        for (int itr = 0; itr < NITER; ++itr) {
            if (t < 1064) ((unsigned int*)nxt)[t] = 0x01010101u;
            __syncthreads();
            for (int e = t; e < (int)E; e += 1024) {
                unsigned int pk = edges[e];
                if (cur[pk >> 16]) nxt[pk & 0xFFFFu] = 0;
            }
            __syncthreads();
            unsigned char* tm = cur; cur = nxt; nxt = tm;
        }
    } else {
        for (int itr = 0; itr < NITER; ++itr) {
            for (int j = t; j < NF; j += 1024) {
                unsigned int d = cnt[j]; if (d > CAPD) d = CAPD;
                const unsigned short* nl = nbr + (size_t)j * CAPD;
                unsigned char kp = 1;
                for (unsigned int e = 0; e < d; ++e)
                    if (cur[nl[e]]) { kp = 0; break; }
                nxt[j] = kp;
            }
            __syncthreads();
            unsigned char* tm = cur; cur = nxt; nxt = tm;
        }
    }
    // final keep & emit (wave-scan prefix)
    int base = t * CH;
    unsigned char kf[CH];
    unsigned int sum = 0;
    #pragma unroll
    for (int q = 0; q < CH; ++q) {
        int j = base + q;
        unsigned char v = 0;
        if (j < NF) v = cur[j] & (unsigned char)(sCV[j] >> 31);
        kf[q] = v; sum += v;
    }
    unsigned int sc2 = sum;
    #pragma unroll
    for (int o = 1; o < 64; o <<= 1) {
        unsigned int n = __shfl_up(sc2, o, 64);
        if (lane >= o) sc2 += n;
    }
    if (lane == 63) wsum[wid] = sc2;
    __syncthreads();
    unsigned int wbase2 = 0, keptTot = 0;
    #pragma unroll
    for (int i = 0; i < 16; ++i) {
        unsigned int v = wsum[i];
        if (i < wid) wbase2 += v;
        keptTot += v;
    }
    unsigned int run = wbase2 + sc2 - sum;    // kept before my first element
    float vy1 = ploc[0], vx1 = ploc[1], vy2 = ploc[2], vx2 = ploc[3];
    float sy = ploc[4] / fmaxf(vy2 - vy1, 1e-6f);
    float sx = ploc[5] / fmaxf(vx2 - vx1, 1e-6f);
    #pragma unroll
    for (int q = 0; q < CH; ++q) {
        int j = base + q;
        if (j >= NF) break;
        unsigned int slot = 0xFFFFFFFFu;
        float scv = 0.0f;
        if (kf[q]) {
            if (run < 100u) { slot = run; scv = sScore[j]; }
            run++;
        } else if (keptTot < 100u) {
            unsigned int nk = (unsigned int)j - run;
            unsigned int s2 = keptTot + nk;
            if (s2 < 100u) { slot = s2; scv = 0.0f; }
        }
        if (slot < 100u) {
            float4 b = sBox[j];
            out[slot * 4 + 0] = (b.x - vy1) * sy;
            out[slot * 4 + 1] = (b.y - vx1) * sx;
            out[slot * 4 + 2] = (b.z - vy1) * sy;
            out[slot * 4 + 3] = (b.w - vx1) * sx;
            out[400 + slot] = (float)(sCV[j] & 0x7Fu);
            out[500 + slot] = scv;
        }
    }
}

extern "C" void kernel_launch(void* const* d_in, const int* in_sizes, int n_in,
                              void* d_out, int out_size, void* d_ws, size_t ws_size,
                              hipStream_t stream) {
    (void)n_in; (void)out_size; (void)ws_size;
    InPtrs P;
    bool inter = (in_sizes[1] == 65536 * 4);
    for (int s = 0; s < 5; ++s) {
        P.cls[s] = (const float*)d_in[inter ? 2 * s : s];
        P.reg[s] = (const float*)d_in[inter ? 2 * s + 1 : 5 + s];
    }
    P.loc = (const float*)d_in[10];

    char* w = (char*)d_ws;
    unsigned int* hist   = (unsigned int*)(w + OFF_HIST);
    unsigned int* cnt    = (unsigned int*)(w + OFF_CNT);
    unsigned int* ctrs   = (unsigned int*)(w + OFF_CTR);
    unsigned int* sbits  = (unsigned int*)(w + OFF_SBITS);
    unsigned int* clsv   = (unsigned int*)(w + OFF_CLSV);
    unsigned int* params = (unsigned int*)(w + OFF_PAR);
    unsigned int* invBlk = (unsigned int*)(w + OFF_INVB);
    unsigned int* invOff = (unsigned int*)(w + OFF_INVO);
    unsigned long long* finKeys = (unsigned long long*)(w + OFF_FINK);
    unsigned long long* bBuf    = (unsigned long long*)(w + OFF_BBUF);
    float4* sBox  = (float4*)(w + OFF_SBOX);
    float* sScore = (float*)(w + OFF_SSC);
    unsigned int* sCV = (unsigned int*)(w + OFF_SCV);
    float* sArea  = (float*)(w + OFF_SAR);
    unsigned short* nbr = (unsigned short*)(w + OFF_NBR);

    hipMemsetAsync(d_ws, 0, ZERO_SZ, stream);
    k1_score<<<NBLK, 1024, 0, stream>>>(P, hist, sbits, clsv, invBlk);
    k2_scan<<<6, 1024, 0, stream>>>(hist, invBlk, params, invOff);
    k3_compact<<<NBLK, 256, 0, stream>>>(sbits, clsv, params, invOff, finKeys, ctrs, bBuf);
    k5_rank<<<266, 256, 0, stream>>>(P, finKeys, ctrs, params, bBuf, sBox, sScore, sCV, sArea);
    k6_adj<<<2278, 256, 0, stream>>>(sBox, sArea, cnt, nbr);
    k7_nms<<<1, 1024, 0, stream>>>(P, sBox, sScore, sCV, cnt, nbr, (float*)d_out);
}